// Round 1
// baseline (453.140 us; speedup 1.0000x reference)
//
#include <hip/hip_runtime.h>
#include <stdint.h>

// ---------------------------------------------------------------------------
// TransformerBlock: pre-LN MHA + pre-LN FFN(GELU), bf16 MFMA internals.
// B=2 S=2048 D=1024 H=16 dk=64 Dff=4096.  All GEMMs are C = A @ B^T with
// A[M,K], Bt[N,K] bf16 row-major (m97 128x128 structure, 16x16x32 MFMA).
// Workspace layout (needs 64 MB):
//   [ 0MB) h_buf   [4096,1024] bf16  (h1 -> attn_cat -> h2, serially reused)
//   [ 8MB) wqkv_t  [3072,1024] bf16
//   [14MB) wo_t    [1024,1024] bf16
//   [16MB) w1_t    [4096,1024] bf16
//   [24MB) w2_t    [1024,4096] bf16
//   [32MB) q_cat   [4096,1024] bf16   } overlapped by ffn1 [4096,4096] bf16
//   [40MB) k_cat   [4096,1024] bf16   } (q/k/vt dead once attention is done)
//   [48MB) vt      [B,H,64,2048] bf16 }
// d_out doubles as x2 (attn residual) between the Wo GEMM and FFN2.
// ---------------------------------------------------------------------------

typedef __attribute__((ext_vector_type(8))) short bf16x8;
typedef __attribute__((ext_vector_type(4))) float f32x4;
typedef __attribute__((ext_vector_type(4))) unsigned short u16x4;

#define DEV __device__ __forceinline__

static constexpr int DM   = 1024;
static constexpr int DFF  = 4096;
static constexpr int NH   = 16;
static constexpr int DKH  = 64;
static constexpr int SEQ  = 2048;
static constexpr int NBAT = 2;
static constexpr int NTOK = NBAT * SEQ;  // 4096

DEV unsigned short f2bf(float f) {
  union { float f; unsigned int u; } v; v.f = f;
  unsigned int u = v.u;
  return (unsigned short)((u + 0x7fffu + ((u >> 16) & 1u)) >> 16);
}

DEV void gload_lds16(const unsigned short* g, unsigned short* l) {
  __builtin_amdgcn_global_load_lds(
      (const __attribute__((address_space(1))) unsigned int*)g,
      (__attribute__((address_space(3))) unsigned int*)l, 16, 0, 0);
}

DEV float rmax16(float v) {
  v = fmaxf(v, __shfl_xor(v, 1));
  v = fmaxf(v, __shfl_xor(v, 2));
  v = fmaxf(v, __shfl_xor(v, 4));
  v = fmaxf(v, __shfl_xor(v, 8));
  return v;
}
DEV float rsum16(float v) {
  v += __shfl_xor(v, 1);
  v += __shfl_xor(v, 2);
  v += __shfl_xor(v, 4);
  v += __shfl_xor(v, 8);
  return v;
}

// ---------------------------------------------------------------------------
// LayerNorm: x fp32 [rows,1024] -> bf16 out. One block (256 thr) per row.
// ---------------------------------------------------------------------------
__global__ __launch_bounds__(256) void ln_kernel(
    const float* __restrict__ x, const float* __restrict__ g,
    const float* __restrict__ be, unsigned short* __restrict__ out) {
  const int row = blockIdx.x;
  const int t = threadIdx.x;
  const int lane = t & 63, w = t >> 6;
  const float4* xr = (const float4*)(x + (size_t)row * DM);
  float4 v = xr[t];
  float s  = v.x + v.y + v.z + v.w;
  float s2 = v.x * v.x + v.y * v.y + v.z * v.z + v.w * v.w;
#pragma unroll
  for (int off = 32; off; off >>= 1) {
    s  += __shfl_down(s, off);
    s2 += __shfl_down(s2, off);
  }
  __shared__ float rs_[4], rq_[4];
  if (lane == 0) { rs_[w] = s; rq_[w] = s2; }
  __syncthreads();
  float fs = rs_[0] + rs_[1] + rs_[2] + rs_[3];
  float fq = rq_[0] + rq_[1] + rq_[2] + rq_[3];
  float mu = fs * (1.0f / DM);
  float var = fq * (1.0f / DM) - mu * mu;
  float rstd = rsqrtf(var + 1e-5f);
  float4 gv = ((const float4*)g)[t];
  float4 bv = ((const float4*)be)[t];
  u16x4 o;
  o[0] = f2bf((v.x - mu) * rstd * gv.x + bv.x);
  o[1] = f2bf((v.y - mu) * rstd * gv.y + bv.y);
  o[2] = f2bf((v.z - mu) * rstd * gv.z + bv.z);
  o[3] = f2bf((v.w - mu) * rstd * gv.w + bv.w);
  *(u16x4*)(out + (size_t)row * DM + t * 4) = o;
}

// ---------------------------------------------------------------------------
// Weight convert: fp32 -> bf16 B^T layouts, one flat grid-stride kernel.
// ---------------------------------------------------------------------------
__global__ __launch_bounds__(256) void convert_weights(
    const float* __restrict__ Wq, const float* __restrict__ Wk,
    const float* __restrict__ Wv, const float* __restrict__ Wo,
    const float* __restrict__ W1, const float* __restrict__ W2,
    unsigned short* __restrict__ wqkv_t, unsigned short* __restrict__ wo_t,
    unsigned short* __restrict__ w1_t, unsigned short* __restrict__ w2_t) {
  const int NQKV = 3 * DM * DM;   // 3,145,728  wqkv_t[n(3072)][d(1024)]
  const int NWO  = DM * DM;       // 1,048,576  wo_t[n(1024)][d(1024)]
  const int NW1  = DM * DFF;      // 4,194,304  w1_t[n(4096)][d(1024)]
  const int NW2  = DM * DFF;      // 4,194,304  w2_t[n(1024)][s(4096)]
  const int total = NQKV + NWO + NW1 + NW2;
  for (int idx = blockIdx.x * 256 + threadIdx.x; idx < total;
       idx += gridDim.x * 256) {
    if (idx < NQKV) {
      int n = idx >> 10, d = idx & 1023;
      int which = n >> 10, nn = n & 1023, h = nn >> 6, kk = nn & 63;
      const float* W = (which == 0) ? Wq : (which == 1) ? Wk : Wv;
      wqkv_t[idx] = f2bf(W[((h << 10) + d) * 64 + kk]);
    } else if (idx < NQKV + NWO) {
      int i = idx - NQKV;
      int n = i >> 10, d = i & 1023;
      wo_t[i] = f2bf(Wo[(d << 10) + n]);
    } else if (idx < NQKV + NWO + NW1) {
      int i = idx - NQKV - NWO;
      int n = i >> 10, d = i & 1023;           // n: 0..4095 (Dff)
      w1_t[i] = f2bf(W1[d * DFF + n]);
    } else {
      int i = idx - NQKV - NWO - NW1;
      int n = i >> 12, s = i & 4095;           // n: 0..1023, s: 0..4095
      w2_t[i] = f2bf(W2[s * DM + n]);
    }
  }
}

// ---------------------------------------------------------------------------
// GEMM: C[M,N] = A[M,K] @ Bt[N,K]^T, bf16 in / fp32 acc. m97 structure:
// 128x128 tile, 4 waves (2x2), 4x4 16x16x32-MFMA acc per wave,
// global_load_lds width-16 staging, 2 barriers per K-step of 32.
// ---------------------------------------------------------------------------
struct EpiArgs {
  unsigned short* q;     // EPI0
  unsigned short* k;     // EPI0
  unsigned short* vt;    // EPI0
  unsigned short* ob16;  // EPI2
  float* of32;           // EPI1 / EPI3
  const float* bias;     // EPI2 / EPI3
  const float* resid;    // EPI1
};

template <int EPI>
__global__ __launch_bounds__(256) void gemm_bt(
    const unsigned short* __restrict__ A, const unsigned short* __restrict__ Bt,
    int M, int N, int K, EpiArgs ep) {
  __shared__ __align__(16) unsigned short Als[128 * 32];
  __shared__ __align__(16) unsigned short Bls[128 * 32];
  const int t = threadIdx.x, lane = t & 63, wave = t >> 6;
  const int wm = wave >> 1, wn = wave & 1;
  const int g = lane >> 4, r16 = lane & 15;
  const int m0 = blockIdx.y * 128, n0 = blockIdx.x * 128;

  f32x4 acc[4][4];
  const f32x4 z4 = {0.f, 0.f, 0.f, 0.f};
#pragma unroll
  for (int i = 0; i < 4; ++i)
#pragma unroll
    for (int j = 0; j < 4; ++j) acc[i][j] = z4;

  for (int k0 = 0; k0 < K; k0 += 32) {
#pragma unroll
    for (int i = 0; i < 2; ++i) {
      const int cb = i * 256 + wave * 64;       // wave-uniform chunk base
      const int c = cb + lane;                  // this lane's 16B chunk
      const int row = c >> 2, cc = (c & 3) * 8; // 4 chunks per 32-elem row
      gload_lds16(A + (size_t)(m0 + row) * K + k0 + cc, &Als[cb * 8]);
      gload_lds16(Bt + (size_t)(n0 + row) * K + k0 + cc, &Bls[cb * 8]);
    }
    __syncthreads();
    bf16x8 af[4], bfr[4];
#pragma unroll
    for (int mt = 0; mt < 4; ++mt)
      af[mt] = *(const bf16x8*)&Als[(wm * 64 + mt * 16 + r16) * 32 + g * 8];
#pragma unroll
    for (int nt = 0; nt < 4; ++nt)
      bfr[nt] = *(const bf16x8*)&Bls[(wn * 64 + nt * 16 + r16) * 32 + g * 8];
#pragma unroll
    for (int mt = 0; mt < 4; ++mt)
#pragma unroll
      for (int nt = 0; nt < 4; ++nt)
        acc[mt][nt] = __builtin_amdgcn_mfma_f32_16x16x32_bf16(
            af[mt], bfr[nt], acc[mt][nt], 0, 0, 0);
    __syncthreads();
  }

  // epilogue: C row = m0+wm*64+mt*16+(lane>>4)*4+r, col = n0+wn*64+nt*16+(lane&15)
#pragma unroll
  for (int mt = 0; mt < 4; ++mt)
#pragma unroll
    for (int nt = 0; nt < 4; ++nt)
#pragma unroll
      for (int r = 0; r < 4; ++r) {
        const int row = m0 + wm * 64 + mt * 16 + g * 4 + r;
        const int col = n0 + wn * 64 + nt * 16 + r16;
        const float v = acc[mt][nt][r];
        if constexpr (EPI == 0) {  // QKV scatter; Q pre-scaled by 1/sqrt(dk)
          if (col < 1024) {
            ep.q[(size_t)row * DM + col] = f2bf(v * 0.125f);
          } else if (col < 2048) {
            ep.k[(size_t)row * DM + (col - 1024)] = f2bf(v);
          } else {
            const int c = col - 2048, hh = c >> 6, dd = c & 63;
            const int bb = row >> 11, ss = row & 2047;
            ep.vt[(((size_t)bb * NH + hh) * DKH + dd) * SEQ + ss] = f2bf(v);
          }
        } else if constexpr (EPI == 1) {  // + residual -> fp32 (x2 into d_out)
          const size_t idx = (size_t)row * N + col;
          ep.of32[idx] = v + ep.resid[idx];
        } else if constexpr (EPI == 2) {  // + bias, exact GELU -> bf16
          const float xx = v + ep.bias[col];
          const float ge = 0.5f * xx * (1.0f + erff(xx * 0.70710678118654752f));
          ep.ob16[(size_t)row * N + col] = f2bf(ge);
        } else {  // EPI 3: + bias + x2 (read d_out) -> d_out fp32
          const size_t idx = (size_t)row * N + col;
          ep.of32[idx] = ep.of32[idx] + v + ep.bias[col];
        }
      }
}

// ---------------------------------------------------------------------------
// Flash attention. Grid (S/128, H, B); 4 waves x 32 q-rows. KV tile = 64.
// Q frags in regs (pre-scaled 1/8); K/V frags straight from global (L2-hot).
// Softmax stats live in C-layout rows (same as O acc -> no cross-lane fixup).
// P -> per-wave XOR-swizzled LDS -> A-frags for PV.  V consumed as Vt[d][s].
// ---------------------------------------------------------------------------
__global__ __launch_bounds__(256) void attn_kernel(
    const unsigned short* __restrict__ Qc, const unsigned short* __restrict__ Kc,
    const unsigned short* __restrict__ Vt, unsigned short* __restrict__ Oc) {
  const int lane = threadIdx.x & 63, wave = threadIdx.x >> 6;
  const int g = lane >> 4, r16 = lane & 15;
  const int h = blockIdx.y, b = blockIdx.z;
  const int q0 = blockIdx.x * 128 + wave * 32;  // per-wave q base (0..2047)
  const size_t rowbase = (size_t)b * SEQ;
  const size_t vhbase = ((size_t)(b * NH + h)) * DKH * SEQ;

  __shared__ __align__(16) unsigned short Pls[4][32 * 64];
  unsigned short* P = &Pls[wave][0];

  bf16x8 qf[2][2];
#pragma unroll
  for (int mt = 0; mt < 2; ++mt)
#pragma unroll
    for (int kt = 0; kt < 2; ++kt)
      qf[mt][kt] = *(const bf16x8*)&Qc[(rowbase + q0 + mt * 16 + r16) * DM +
                                       h * DKH + kt * 32 + g * 8];

  const f32x4 z4 = {0.f, 0.f, 0.f, 0.f};
  f32x4 o[2][4];
  float mrun[2][4], lrun[2][4];
#pragma unroll
  for (int mt = 0; mt < 2; ++mt) {
#pragma unroll
    for (int dt = 0; dt < 4; ++dt) o[mt][dt] = z4;
#pragma unroll
    for (int r = 0; r < 4; ++r) { mrun[mt][r] = -1e30f; lrun[mt][r] = 0.f; }
  }

  for (int s0 = 0; s0 < SEQ; s0 += 64) {
    // ---- S = Q K^T (scaled) ----
    f32x4 sacc[2][4];
#pragma unroll
    for (int mt = 0; mt < 2; ++mt)
#pragma unroll
      for (int nt = 0; nt < 4; ++nt) sacc[mt][nt] = z4;
#pragma unroll
    for (int nt = 0; nt < 4; ++nt)
#pragma unroll
      for (int kt = 0; kt < 2; ++kt) {
        bf16x8 kf = *(const bf16x8*)&Kc[(rowbase + s0 + nt * 16 + r16) * DM +
                                        h * DKH + kt * 32 + g * 8];
#pragma unroll
        for (int mt = 0; mt < 2; ++mt)
          sacc[mt][nt] = __builtin_amdgcn_mfma_f32_16x16x32_bf16(
              qf[mt][kt], kf, sacc[mt][nt], 0, 0, 0);
      }
    // ---- online softmax (rows = q = g*4+r, matching O layout) ----
#pragma unroll
    for (int mt = 0; mt < 2; ++mt)
#pragma unroll
      for (int r = 0; r < 4; ++r) {
        float mx = sacc[mt][0][r];
#pragma unroll
        for (int nt = 1; nt < 4; ++nt) mx = fmaxf(mx, sacc[mt][nt][r]);
        mx = rmax16(mx);
        const float mnew = fmaxf(mrun[mt][r], mx);
        const float corr = __expf(mrun[mt][r] - mnew);
        float psum = 0.f;
#pragma unroll
        for (int nt = 0; nt < 4; ++nt) {
          const float p = __expf(sacc[mt][nt][r] - mnew);
          sacc[mt][nt][r] = p;
          psum += p;
        }
        psum = rsum16(psum);
        lrun[mt][r] = lrun[mt][r] * corr + psum;
        mrun[mt][r] = mnew;
#pragma unroll
        for (int dt = 0; dt < 4; ++dt) o[mt][dt][r] *= corr;
      }
    // ---- P -> LDS (bf16, chunk ^= q&7 swizzle) ----
#pragma unroll
    for (int mt = 0; mt < 2; ++mt)
#pragma unroll
      for (int nt = 0; nt < 4; ++nt)
#pragma unroll
        for (int r = 0; r < 4; ++r) {
          const int q = mt * 16 + g * 4 + r;
          const int sl = nt * 16 + r16;
          P[q * 64 + (((sl >> 3) ^ (q & 7)) << 3) + (sl & 7)] =
              f2bf(sacc[mt][nt][r]);
        }
    // per-wave buffer: no __syncthreads needed; compiler orders LDS ops.
    // ---- O += P V ----
#pragma unroll
    for (int kt = 0; kt < 2; ++kt) {
      bf16x8 pf[2];
#pragma unroll
      for (int mt = 0; mt < 2; ++mt) {
        const int q = mt * 16 + r16;
        const int c = kt * 4 + g;
        pf[mt] = *(const bf16x8*)&P[q * 64 + ((c ^ (q & 7)) << 3)];
      }
#pragma unroll
      for (int dt = 0; dt < 4; ++dt) {
        bf16x8 vf = *(const bf16x8*)&Vt[vhbase + (size_t)(dt * 16 + r16) * SEQ +
                                        s0 + kt * 32 + g * 8];
#pragma unroll
        for (int mt = 0; mt < 2; ++mt)
          o[mt][dt] = __builtin_amdgcn_mfma_f32_16x16x32_bf16(
              pf[mt], vf, o[mt][dt], 0, 0, 0);
      }
    }
  }
  // ---- finalize: O /= l, write bf16 into attn_cat ----
#pragma unroll
  for (int mt = 0; mt < 2; ++mt)
#pragma unroll
    for (int r = 0; r < 4; ++r) {
      const float inv = 1.0f / lrun[mt][r];
      const int row = q0 + mt * 16 + g * 4 + r;
#pragma unroll
      for (int dt = 0; dt < 4; ++dt) {
        const int col = h * DKH + dt * 16 + r16;
        Oc[(rowbase + row) * DM + col] = f2bf(o[mt][dt][r] * inv);
      }
    }
}

// ---------------------------------------------------------------------------
extern "C" void kernel_launch(void* const* d_in, const int* in_sizes, int n_in,
                              void* d_out, int out_size, void* d_ws,
                              size_t ws_size, hipStream_t stream) {
  (void)in_sizes; (void)n_in; (void)out_size; (void)ws_size;
  const float* x   = (const float*)d_in[0];
  const float* Wq  = (const float*)d_in[1];
  const float* Wk  = (const float*)d_in[2];
  const float* Wv  = (const float*)d_in[3];
  const float* Wo  = (const float*)d_in[4];
  const float* W1  = (const float*)d_in[5];
  const float* b1  = (const float*)d_in[6];
  const float* W2  = (const float*)d_in[7];
  const float* b2  = (const float*)d_in[8];
  const float* g1  = (const float*)d_in[9];
  const float* be1 = (const float*)d_in[10];
  const float* g2  = (const float*)d_in[11];
  const float* be2 = (const float*)d_in[12];
  float* out = (float*)d_out;

  char* ws = (char*)d_ws;
  const size_t MB = 1024 * 1024;
  unsigned short* h_buf  = (unsigned short*)(ws + 0 * MB);
  unsigned short* wqkv_t = (unsigned short*)(ws + 8 * MB);
  unsigned short* wo_t   = (unsigned short*)(ws + 14 * MB);
  unsigned short* w1_t   = (unsigned short*)(ws + 16 * MB);
  unsigned short* w2_t   = (unsigned short*)(ws + 24 * MB);
  unsigned short* q_cat  = (unsigned short*)(ws + 32 * MB);
  unsigned short* k_cat  = (unsigned short*)(ws + 40 * MB);
  unsigned short* vt_buf = (unsigned short*)(ws + 48 * MB);
  unsigned short* ffn1   = (unsigned short*)(ws + 32 * MB);  // overlaps q/k/vt

  EpiArgs e0 = {}; e0.q = q_cat; e0.k = k_cat; e0.vt = vt_buf;
  EpiArgs e1 = {}; e1.of32 = out; e1.resid = x;
  EpiArgs e2 = {}; e2.ob16 = ffn1; e2.bias = b1;
  EpiArgs e3 = {}; e3.of32 = out; e3.bias = b2;

  convert_weights<<<12288, 256, 0, stream>>>(Wq, Wk, Wv, Wo, W1, W2,
                                             wqkv_t, wo_t, w1_t, w2_t);
  ln_kernel<<<NTOK, 256, 0, stream>>>(x, g1, be1, h_buf);
  gemm_bt<0><<<dim3(3072 / 128, NTOK / 128), 256, 0, stream>>>(
      h_buf, wqkv_t, NTOK, 3072, DM, e0);
  attn_kernel<<<dim3(SEQ / 128, NH, NBAT), 256, 0, stream>>>(
      q_cat, k_cat, vt_buf, h_buf);
  gemm_bt<1><<<dim3(DM / 128, NTOK / 128), 256, 0, stream>>>(
      h_buf, wo_t, NTOK, DM, DM, e1);
  ln_kernel<<<NTOK, 256, 0, stream>>>(out, g2, be2, h_buf);
  gemm_bt<2><<<dim3(DFF / 128, NTOK / 128), 256, 0, stream>>>(
      h_buf, w1_t, NTOK, DFF, DM, e2);
  gemm_bt<3><<<dim3(DM / 128, NTOK / 128), 256, 0, stream>>>(
      ffn1, w2_t, NTOK, DM, DFF, e3);
}

// Round 2
// 433.252 us; speedup vs baseline: 1.0459x; 1.0459x over previous
//
#include <hip/hip_runtime.h>
#include <stdint.h>

// ---------------------------------------------------------------------------
// TransformerBlock: pre-LN MHA + pre-LN FFN(GELU), bf16 MFMA internals.
// B=2 S=2048 D=1024 H=16 dk=64 Dff=4096.  GEMMs: C = A @ B^T, m97 structure.
// Attention: swapped-operand 32x32x16 MFMA flash attention, softmax fully
// in-register (q = lane&31 for QK^T *and* PV outputs), P packed to bf16 via
// v_cvt_pk_bf16_f32.  V scratch stored with kv bits 2<->3 swapped so the
// MFMA contraction permutation needs no cross-lane data movement.
// Workspace layout (needs 64 MB):
//   [ 0MB) h_buf   [4096,1024] bf16  (h1 -> attn_cat -> h2, serially reused)
//   [ 8MB) wqkv_t  [3072,1024] bf16
//   [14MB) wo_t    [1024,1024] bf16
//   [16MB) w1_t    [4096,1024] bf16
//   [24MB) w2_t    [1024,4096] bf16
//   [32MB) q_cat   [4096,1024] bf16   } overlapped by ffn1 [4096,4096] bf16
//   [40MB) k_cat   [4096,1024] bf16   } (q/k/vt dead once attention is done)
//   [48MB) vt      [B,H,64,2048] bf16 (kv index bit2<->bit3 swizzled)
// d_out doubles as x2 (attn residual) between the Wo GEMM and FFN2.
// ---------------------------------------------------------------------------

typedef __attribute__((ext_vector_type(8))) short bf16x8;
typedef __attribute__((ext_vector_type(4))) float f32x4;
typedef __attribute__((ext_vector_type(16))) float f32x16;
typedef __attribute__((ext_vector_type(4))) unsigned short u16x4;
typedef __attribute__((ext_vector_type(4))) unsigned int u32x4;

#define DEV __device__ __forceinline__

static constexpr int DM   = 1024;
static constexpr int DFF  = 4096;
static constexpr int NH   = 16;
static constexpr int DKH  = 64;
static constexpr int SEQ  = 2048;
static constexpr int NBAT = 2;
static constexpr int NTOK = NBAT * SEQ;  // 4096

DEV unsigned short f2bf(float f) {
  union { float f; unsigned int u; } v; v.f = f;
  unsigned int u = v.u;
  return (unsigned short)((u + 0x7fffu + ((u >> 16) & 1u)) >> 16);
}

DEV void gload_lds16(const unsigned short* g, unsigned short* l) {
  __builtin_amdgcn_global_load_lds(
      (const __attribute__((address_space(1))) unsigned int*)g,
      (__attribute__((address_space(3))) unsigned int*)l, 16, 0, 0);
}

// ---------------------------------------------------------------------------
// LayerNorm: x fp32 [rows,1024] -> bf16 out. One block (256 thr) per row.
// ---------------------------------------------------------------------------
__global__ __launch_bounds__(256) void ln_kernel(
    const float* __restrict__ x, const float* __restrict__ g,
    const float* __restrict__ be, unsigned short* __restrict__ out) {
  const int row = blockIdx.x;
  const int t = threadIdx.x;
  const int lane = t & 63, w = t >> 6;
  const float4* xr = (const float4*)(x + (size_t)row * DM);
  float4 v = xr[t];
  float s  = v.x + v.y + v.z + v.w;
  float s2 = v.x * v.x + v.y * v.y + v.z * v.z + v.w * v.w;
#pragma unroll
  for (int off = 32; off; off >>= 1) {
    s  += __shfl_down(s, off);
    s2 += __shfl_down(s2, off);
  }
  __shared__ float rs_[4], rq_[4];
  if (lane == 0) { rs_[w] = s; rq_[w] = s2; }
  __syncthreads();
  float fs = rs_[0] + rs_[1] + rs_[2] + rs_[3];
  float fq = rq_[0] + rq_[1] + rq_[2] + rq_[3];
  float mu = fs * (1.0f / DM);
  float var = fq * (1.0f / DM) - mu * mu;
  float rstd = rsqrtf(var + 1e-5f);
  float4 gv = ((const float4*)g)[t];
  float4 bv = ((const float4*)be)[t];
  u16x4 o;
  o[0] = f2bf((v.x - mu) * rstd * gv.x + bv.x);
  o[1] = f2bf((v.y - mu) * rstd * gv.y + bv.y);
  o[2] = f2bf((v.z - mu) * rstd * gv.z + bv.z);
  o[3] = f2bf((v.w - mu) * rstd * gv.w + bv.w);
  *(u16x4*)(out + (size_t)row * DM + t * 4) = o;
}

// ---------------------------------------------------------------------------
// Weight convert: fp32 -> bf16 B^T layouts, one flat grid-stride kernel.
// ---------------------------------------------------------------------------
__global__ __launch_bounds__(256) void convert_weights(
    const float* __restrict__ Wq, const float* __restrict__ Wk,
    const float* __restrict__ Wv, const float* __restrict__ Wo,
    const float* __restrict__ W1, const float* __restrict__ W2,
    unsigned short* __restrict__ wqkv_t, unsigned short* __restrict__ wo_t,
    unsigned short* __restrict__ w1_t, unsigned short* __restrict__ w2_t) {
  const int NQKV = 3 * DM * DM;   // wqkv_t[n(3072)][d(1024)]
  const int NWO  = DM * DM;       // wo_t[n(1024)][d(1024)]
  const int NW1  = DM * DFF;      // w1_t[n(4096)][d(1024)]
  const int NW2  = DM * DFF;      // w2_t[n(1024)][s(4096)]
  const int total = NQKV + NWO + NW1 + NW2;
  for (int idx = blockIdx.x * 256 + threadIdx.x; idx < total;
       idx += gridDim.x * 256) {
    if (idx < NQKV) {
      int n = idx >> 10, d = idx & 1023;
      int which = n >> 10, nn = n & 1023, h = nn >> 6, kk = nn & 63;
      const float* W = (which == 0) ? Wq : (which == 1) ? Wk : Wv;
      wqkv_t[idx] = f2bf(W[((h << 10) + d) * 64 + kk]);
    } else if (idx < NQKV + NWO) {
      int i = idx - NQKV;
      int n = i >> 10, d = i & 1023;
      wo_t[i] = f2bf(Wo[(d << 10) + n]);
    } else if (idx < NQKV + NWO + NW1) {
      int i = idx - NQKV - NWO;
      int n = i >> 10, d = i & 1023;           // n: 0..4095 (Dff)
      w1_t[i] = f2bf(W1[d * DFF + n]);
    } else {
      int i = idx - NQKV - NWO - NW1;
      int n = i >> 12, s = i & 4095;           // n: 0..1023, s: 0..4095
      w2_t[i] = f2bf(W2[s * DM + n]);
    }
  }
}

// ---------------------------------------------------------------------------
// GEMM: C[M,N] = A[M,K] @ Bt[N,K]^T, bf16 in / fp32 acc. m97 structure:
// 128x128 tile, 4 waves (2x2), 4x4 16x16x32-MFMA acc per wave,
// global_load_lds width-16 staging, 2 barriers per K-step of 32.
// ---------------------------------------------------------------------------
struct EpiArgs {
  unsigned short* q;     // EPI0
  unsigned short* k;     // EPI0
  unsigned short* vt;    // EPI0
  unsigned short* ob16;  // EPI2
  float* of32;           // EPI1 / EPI3
  const float* bias;     // EPI2 / EPI3
  const float* resid;    // EPI1
};

template <int EPI>
__global__ __launch_bounds__(256) void gemm_bt(
    const unsigned short* __restrict__ A, const unsigned short* __restrict__ Bt,
    int M, int N, int K, EpiArgs ep) {
  __shared__ __align__(16) unsigned short Als[128 * 32];
  __shared__ __align__(16) unsigned short Bls[128 * 32];
  const int t = threadIdx.x, lane = t & 63, wave = t >> 6;
  const int wm = wave >> 1, wn = wave & 1;
  const int g = lane >> 4, r16 = lane & 15;
  const int m0 = blockIdx.y * 128, n0 = blockIdx.x * 128;

  f32x4 acc[4][4];
  const f32x4 z4 = {0.f, 0.f, 0.f, 0.f};
#pragma unroll
  for (int i = 0; i < 4; ++i)
#pragma unroll
    for (int j = 0; j < 4; ++j) acc[i][j] = z4;

  for (int k0 = 0; k0 < K; k0 += 32) {
#pragma unroll
    for (int i = 0; i < 2; ++i) {
      const int cb = i * 256 + wave * 64;       // wave-uniform chunk base
      const int c = cb + lane;                  // this lane's 16B chunk
      const int row = c >> 2, cc = (c & 3) * 8; // 4 chunks per 32-elem row
      gload_lds16(A + (size_t)(m0 + row) * K + k0 + cc, &Als[cb * 8]);
      gload_lds16(Bt + (size_t)(n0 + row) * K + k0 + cc, &Bls[cb * 8]);
    }
    __syncthreads();
    bf16x8 af[4], bfr[4];
#pragma unroll
    for (int mt = 0; mt < 4; ++mt)
      af[mt] = *(const bf16x8*)&Als[(wm * 64 + mt * 16 + r16) * 32 + g * 8];
#pragma unroll
    for (int nt = 0; nt < 4; ++nt)
      bfr[nt] = *(const bf16x8*)&Bls[(wn * 64 + nt * 16 + r16) * 32 + g * 8];
#pragma unroll
    for (int mt = 0; mt < 4; ++mt)
#pragma unroll
      for (int nt = 0; nt < 4; ++nt)
        acc[mt][nt] = __builtin_amdgcn_mfma_f32_16x16x32_bf16(
            af[mt], bfr[nt], acc[mt][nt], 0, 0, 0);
    __syncthreads();
  }

  // epilogue: C row = m0+wm*64+mt*16+(lane>>4)*4+r, col = n0+wn*64+nt*16+(lane&15)
#pragma unroll
  for (int mt = 0; mt < 4; ++mt)
#pragma unroll
    for (int nt = 0; nt < 4; ++nt)
#pragma unroll
      for (int r = 0; r < 4; ++r) {
        const int row = m0 + wm * 64 + mt * 16 + g * 4 + r;
        const int col = n0 + wn * 64 + nt * 16 + r16;
        const float v = acc[mt][nt][r];
        if constexpr (EPI == 0) {  // QKV scatter; Q pre-scaled by 1/sqrt(dk)
          if (col < 1024) {
            ep.q[(size_t)row * DM + col] = f2bf(v * 0.125f);
          } else if (col < 2048) {
            ep.k[(size_t)row * DM + (col - 1024)] = f2bf(v);
          } else {
            const int c = col - 2048, hh = c >> 6, dd = c & 63;
            const int bb = row >> 11, ss = row & 2047;
            // kv bit2<->bit3 swizzle (matches attn PV contraction permutation)
            const int ssw = (ss & ~12) | ((ss & 4) << 1) | ((ss & 8) >> 1);
            ep.vt[(((size_t)bb * NH + hh) * DKH + dd) * SEQ + ssw] = f2bf(v);
          }
        } else if constexpr (EPI == 1) {  // + residual -> fp32 (x2 into d_out)
          const size_t idx = (size_t)row * N + col;
          ep.of32[idx] = v + ep.resid[idx];
        } else if constexpr (EPI == 2) {  // + bias, exact GELU -> bf16
          const float xx = v + ep.bias[col];
          const float ge = 0.5f * xx * (1.0f + erff(xx * 0.70710678118654752f));
          ep.ob16[(size_t)row * N + col] = f2bf(ge);
        } else {  // EPI 3: + bias + x2 (read d_out) -> d_out fp32
          const size_t idx = (size_t)row * N + col;
          ep.of32[idx] = ep.of32[idx] + v + ep.bias[col];
        }
      }
}

// ---------------------------------------------------------------------------
// Flash attention, swapped-operand 32x32x16 form. Grid (S/128, H, B);
// 4 waves x 32 q-rows; KV step 64 (2x32 windows).
//   QK^T: p = mfma(Kfrag, Qfrag):  C col = lane&31 = q (lane-local rows!)
//         C row = kv = (reg&3) + 8*(reg>>2) + 4*(lane>>5)
//   softmax: all state (m, l) scalar per lane; defer-max THR=8 (T13).
//   P pack: frag elem e (half hi) = p[8*ks + e]  (v_cvt_pk_bf16_f32 pairs),
//         valid because V is stored kv-bit2<->3-swizzled: both MFMA operands
//         see the same contraction-index permutation.
//   PV:  o[dblk] = mfma(Vtfrag, Pfrag): C col = q again -> scalar rescale.
// No LDS, no barriers, no cross-lane ops except 2 shfl_xor per 64 kv.
// ---------------------------------------------------------------------------
__global__ __launch_bounds__(256, 2) void attn_kernel(
    const unsigned short* __restrict__ Qc, const unsigned short* __restrict__ Kc,
    const unsigned short* __restrict__ Vt, unsigned short* __restrict__ Oc) {
  const int lane = threadIdx.x & 63, wave = threadIdx.x >> 6;
  const int hi = lane >> 5, l31 = lane & 31;
  const int h = blockIdx.y, b = blockIdx.z;
  const int q0 = blockIdx.x * 128 + wave * 32;
  const size_t rowbase = (size_t)b * SEQ;
  const size_t vbase = ((size_t)(b * NH + h)) * DKH * SEQ;

  // Q B-frags: lane holds q = q0+l31, dk = kk*16 + hi*8 + e  (Q pre-scaled)
  bf16x8 qf[4];
  const unsigned short* qp = Qc + (rowbase + q0 + l31) * DM + h * DKH + hi * 8;
#pragma unroll
  for (int kk = 0; kk < 4; ++kk) qf[kk] = *(const bf16x8*)(qp + kk * 16);

  f32x16 o0, o1;
#pragma unroll
  for (int r = 0; r < 16; ++r) { o0[r] = 0.f; o1[r] = 0.f; }
  float m = -1e30f, lsum = 0.f;

  const unsigned short* kp = Kc + (rowbase + l31) * DM + h * DKH + hi * 8;
  const unsigned short* vp = Vt + vbase + (size_t)l31 * SEQ + hi * 8;

  for (int s0 = 0; s0 < SEQ; s0 += 64) {
    // ---- K A-frags for both 32-kv halves (issue all loads up front) ----
    bf16x8 kfA[4], kfB[4];
#pragma unroll
    for (int kk = 0; kk < 4; ++kk) {
      kfA[kk] = *(const bf16x8*)(kp + (size_t)s0 * DM + kk * 16);
      kfB[kk] = *(const bf16x8*)(kp + (size_t)(s0 + 32) * DM + kk * 16);
    }
    // ---- V A-frags: lane d = dblk*32+l31, window w: swizzled-contiguous ----
    bf16x8 vf[2][4];
#pragma unroll
    for (int dblk = 0; dblk < 2; ++dblk)
#pragma unroll
      for (int w = 0; w < 4; ++w)
        vf[dblk][w] =
            *(const bf16x8*)(vp + (size_t)(dblk * 32) * SEQ + s0 + w * 16);
    // ---- S^T = K Q^T ----
    f32x16 pA, pB;
#pragma unroll
    for (int r = 0; r < 16; ++r) { pA[r] = 0.f; pB[r] = 0.f; }
#pragma unroll
    for (int kk = 0; kk < 4; ++kk) {
      pA = __builtin_amdgcn_mfma_f32_32x32x16_bf16(kfA[kk], qf[kk], pA, 0, 0, 0);
      pB = __builtin_amdgcn_mfma_f32_32x32x16_bf16(kfB[kk], qf[kk], pB, 0, 0, 0);
    }
    // ---- online softmax, all lane-local (q = l31) ----
    float mx = fmaxf(pA[0], pB[0]);
#pragma unroll
    for (int r = 1; r < 16; ++r) mx = fmaxf(mx, fmaxf(pA[r], pB[r]));
    mx = fmaxf(mx, __shfl_xor(mx, 32));
    if (__any(mx > m + 8.f)) {  // defer-max: skip rescale on small growth
      const float mnew = fmaxf(m, mx);
      const float corr = __expf(m - mnew);
#pragma unroll
      for (int r = 0; r < 16; ++r) { o0[r] *= corr; o1[r] *= corr; }
      lsum *= corr;
      m = mnew;
    }
    float ps = 0.f;
#pragma unroll
    for (int r = 0; r < 16; ++r) {
      pA[r] = __expf(pA[r] - m); ps += pA[r];
      pB[r] = __expf(pB[r] - m); ps += pB[r];
    }
    ps += __shfl_xor(ps, 32);
    lsum += ps;
    // ---- pack P -> bf16 B-frags (4 windows of 16 kv) ----
    bf16x8 pw[4];
#pragma unroll
    for (int w = 0; w < 4; ++w) {
      unsigned int wd0, wd1, wd2, wd3;
      const int e0 = (w & 1) * 8;
      if (w < 2) {
        asm("v_cvt_pk_bf16_f32 %0, %1, %2" : "=v"(wd0) : "v"(pA[e0 + 0]), "v"(pA[e0 + 1]));
        asm("v_cvt_pk_bf16_f32 %0, %1, %2" : "=v"(wd1) : "v"(pA[e0 + 2]), "v"(pA[e0 + 3]));
        asm("v_cvt_pk_bf16_f32 %0, %1, %2" : "=v"(wd2) : "v"(pA[e0 + 4]), "v"(pA[e0 + 5]));
        asm("v_cvt_pk_bf16_f32 %0, %1, %2" : "=v"(wd3) : "v"(pA[e0 + 6]), "v"(pA[e0 + 7]));
      } else {
        asm("v_cvt_pk_bf16_f32 %0, %1, %2" : "=v"(wd0) : "v"(pB[e0 + 0]), "v"(pB[e0 + 1]));
        asm("v_cvt_pk_bf16_f32 %0, %1, %2" : "=v"(wd1) : "v"(pB[e0 + 2]), "v"(pB[e0 + 3]));
        asm("v_cvt_pk_bf16_f32 %0, %1, %2" : "=v"(wd2) : "v"(pB[e0 + 4]), "v"(pB[e0 + 5]));
        asm("v_cvt_pk_bf16_f32 %0, %1, %2" : "=v"(wd3) : "v"(pB[e0 + 6]), "v"(pB[e0 + 7]));
      }
      u32x4 wv = {wd0, wd1, wd2, wd3};
      pw[w] = __builtin_bit_cast(bf16x8, wv);
    }
    // ---- O^T += (P V)^T ----
#pragma unroll
    for (int w = 0; w < 4; ++w) {
      o0 = __builtin_amdgcn_mfma_f32_32x32x16_bf16(vf[0][w], pw[w], o0, 0, 0, 0);
      o1 = __builtin_amdgcn_mfma_f32_32x32x16_bf16(vf[1][w], pw[w], o1, 0, 0, 0);
    }
  }
  // ---- finalize: O /= l, write bf16 (row q = l31 scalar per lane) ----
  const float inv = 1.0f / lsum;
  unsigned short* op = Oc + (rowbase + q0 + l31) * DM + h * DKH + hi * 4;
#pragma unroll
  for (int dblk = 0; dblk < 2; ++dblk)
#pragma unroll
    for (int g4 = 0; g4 < 4; ++g4) {  // d = dblk*32 + g4*8 + hi*4 + r
      u16x4 st;
#pragma unroll
      for (int r = 0; r < 4; ++r) {
        const float v = (dblk ? o1[g4 * 4 + r] : o0[g4 * 4 + r]) * inv;
        st[r] = f2bf(v);
      }
      *(u16x4*)(op + dblk * 32 + g4 * 8) = st;
    }
}

// ---------------------------------------------------------------------------
extern "C" void kernel_launch(void* const* d_in, const int* in_sizes, int n_in,
                              void* d_out, int out_size, void* d_ws,
                              size_t ws_size, hipStream_t stream) {
  (void)in_sizes; (void)n_in; (void)out_size; (void)ws_size;
  const float* x   = (const float*)d_in[0];
  const float* Wq  = (const float*)d_in[1];
  const float* Wk  = (const float*)d_in[2];
  const float* Wv  = (const float*)d_in[3];
  const float* Wo  = (const float*)d_in[4];
  const float* W1  = (const float*)d_in[5];
  const float* b1  = (const float*)d_in[6];
  const float* W2  = (const float*)d_in[7];
  const float* b2  = (const float*)d_in[8];
  const float* g1  = (const float*)d_in[9];
  const float* be1 = (const float*)d_in[10];
  const float* g2  = (const float*)d_in[11];
  const float* be2 = (const float*)d_in[12];
  float* out = (float*)d_out;

  char* ws = (char*)d_ws;
  const size_t MB = 1024 * 1024;
  unsigned short* h_buf  = (unsigned short*)(ws + 0 * MB);
  unsigned short* wqkv_t = (unsigned short*)(ws + 8 * MB);
  unsigned short* wo_t   = (unsigned short*)(ws + 14 * MB);
  unsigned short* w1_t   = (unsigned short*)(ws + 16 * MB);
  unsigned short* w2_t   = (unsigned short*)(ws + 24 * MB);
  unsigned short* q_cat  = (unsigned short*)(ws + 32 * MB);
  unsigned short* k_cat  = (unsigned short*)(ws + 40 * MB);
  unsigned short* vt_buf = (unsigned short*)(ws + 48 * MB);
  unsigned short* ffn1   = (unsigned short*)(ws + 32 * MB);  // overlaps q/k/vt

  EpiArgs e0 = {}; e0.q = q_cat; e0.k = k_cat; e0.vt = vt_buf;
  EpiArgs e1 = {}; e1.of32 = out; e1.resid = x;
  EpiArgs e2 = {}; e2.ob16 = ffn1; e2.bias = b1;
  EpiArgs e3 = {}; e3.of32 = out; e3.bias = b2;

  convert_weights<<<12288, 256, 0, stream>>>(Wq, Wk, Wv, Wo, W1, W2,
                                             wqkv_t, wo_t, w1_t, w2_t);
  ln_kernel<<<NTOK, 256, 0, stream>>>(x, g1, be1, h_buf);
  gemm_bt<0><<<dim3(3072 / 128, NTOK / 128), 256, 0, stream>>>(
      h_buf, wqkv_t, NTOK, 3072, DM, e0);
  attn_kernel<<<dim3(SEQ / 128, NH, NBAT), 256, 0, stream>>>(
      q_cat, k_cat, vt_buf, h_buf);
  gemm_bt<1><<<dim3(DM / 128, NTOK / 128), 256, 0, stream>>>(
      h_buf, wo_t, NTOK, DM, DM, e1);
  ln_kernel<<<NTOK, 256, 0, stream>>>(out, g2, be2, h_buf);
  gemm_bt<2><<<dim3(DFF / 128, NTOK / 128), 256, 0, stream>>>(
      h_buf, w1_t, NTOK, DFF, DM, e2);
  gemm_bt<3><<<dim3(DM / 128, NTOK / 128), 256, 0, stream>>>(
      ffn1, w2_t, NTOK, DM, DFF, e3);
}

// Round 3
// 431.276 us; speedup vs baseline: 1.0507x; 1.0046x over previous
//
#include <hip/hip_runtime.h>
#include <stdint.h>

// ---------------------------------------------------------------------------
// TransformerBlock: pre-LN MHA + pre-LN FFN(GELU), bf16 MFMA internals.
// B=2 S=2048 D=1024 H=16 dk=64 Dff=4096.  GEMMs: C = A @ B^T, m97 structure.
// Attention: swapped-operand 32x32x16 MFMA flash attention, softmax fully
// in-register; R3 adds (a) K double-buffer prefetch + V issued at tile top
// (latency hiding), (b) XCD-group block remap so all q-blocks of one (b,h)
// share an XCD L2 (K/V slice 512KB, 4 groups/XCD = 2MB < 4MB L2),
// (c) s_setprio around MFMA clusters.
// Workspace layout (64 MB):
//   [ 0MB) h_buf   [4096,1024] bf16  (h1 -> attn_cat -> h2, serially reused)
//   [ 8MB) wqkv_t  [3072,1024] bf16
//   [14MB) wo_t    [1024,1024] bf16
//   [16MB) w1_t    [4096,1024] bf16
//   [24MB) w2_t    [1024,4096] bf16
//   [32MB) q_cat   [4096,1024] bf16   } overlapped by ffn1 [4096,4096] bf16
//   [40MB) k_cat   [4096,1024] bf16   } (q/k/vt dead once attention is done)
//   [48MB) vt      [B,H,64,2048] bf16 (kv index bit2<->bit3 swizzled)
// d_out doubles as x2 (attn residual) between the Wo GEMM and FFN2.
// ---------------------------------------------------------------------------

typedef __attribute__((ext_vector_type(8))) short bf16x8;
typedef __attribute__((ext_vector_type(4))) float f32x4;
typedef __attribute__((ext_vector_type(16))) float f32x16;
typedef __attribute__((ext_vector_type(4))) unsigned short u16x4;
typedef __attribute__((ext_vector_type(4))) unsigned int u32x4;

#define DEV __device__ __forceinline__

static constexpr int DM   = 1024;
static constexpr int DFF  = 4096;
static constexpr int NH   = 16;
static constexpr int DKH  = 64;
static constexpr int SEQ  = 2048;
static constexpr int NBAT = 2;
static constexpr int NTOK = NBAT * SEQ;  // 4096

DEV unsigned short f2bf(float f) {
  union { float f; unsigned int u; } v; v.f = f;
  unsigned int u = v.u;
  return (unsigned short)((u + 0x7fffu + ((u >> 16) & 1u)) >> 16);
}

DEV void gload_lds16(const unsigned short* g, unsigned short* l) {
  __builtin_amdgcn_global_load_lds(
      (const __attribute__((address_space(1))) unsigned int*)g,
      (__attribute__((address_space(3))) unsigned int*)l, 16, 0, 0);
}

// ---------------------------------------------------------------------------
// LayerNorm: x fp32 [rows,1024] -> bf16 out. One block (256 thr) per row.
// ---------------------------------------------------------------------------
__global__ __launch_bounds__(256) void ln_kernel(
    const float* __restrict__ x, const float* __restrict__ g,
    const float* __restrict__ be, unsigned short* __restrict__ out) {
  const int row = blockIdx.x;
  const int t = threadIdx.x;
  const int lane = t & 63, w = t >> 6;
  const float4* xr = (const float4*)(x + (size_t)row * DM);
  float4 v = xr[t];
  float s  = v.x + v.y + v.z + v.w;
  float s2 = v.x * v.x + v.y * v.y + v.z * v.z + v.w * v.w;
#pragma unroll
  for (int off = 32; off; off >>= 1) {
    s  += __shfl_down(s, off);
    s2 += __shfl_down(s2, off);
  }
  __shared__ float rs_[4], rq_[4];
  if (lane == 0) { rs_[w] = s; rq_[w] = s2; }
  __syncthreads();
  float fs = rs_[0] + rs_[1] + rs_[2] + rs_[3];
  float fq = rq_[0] + rq_[1] + rq_[2] + rq_[3];
  float mu = fs * (1.0f / DM);
  float var = fq * (1.0f / DM) - mu * mu;
  float rstd = rsqrtf(var + 1e-5f);
  float4 gv = ((const float4*)g)[t];
  float4 bv = ((const float4*)be)[t];
  u16x4 o;
  o[0] = f2bf((v.x - mu) * rstd * gv.x + bv.x);
  o[1] = f2bf((v.y - mu) * rstd * gv.y + bv.y);
  o[2] = f2bf((v.z - mu) * rstd * gv.z + bv.z);
  o[3] = f2bf((v.w - mu) * rstd * gv.w + bv.w);
  *(u16x4*)(out + (size_t)row * DM + t * 4) = o;
}

// ---------------------------------------------------------------------------
// Weight convert: fp32 -> bf16 B^T layouts, one flat grid-stride kernel.
// ---------------------------------------------------------------------------
__global__ __launch_bounds__(256) void convert_weights(
    const float* __restrict__ Wq, const float* __restrict__ Wk,
    const float* __restrict__ Wv, const float* __restrict__ Wo,
    const float* __restrict__ W1, const float* __restrict__ W2,
    unsigned short* __restrict__ wqkv_t, unsigned short* __restrict__ wo_t,
    unsigned short* __restrict__ w1_t, unsigned short* __restrict__ w2_t) {
  const int NQKV = 3 * DM * DM;   // wqkv_t[n(3072)][d(1024)]
  const int NWO  = DM * DM;       // wo_t[n(1024)][d(1024)]
  const int NW1  = DM * DFF;      // w1_t[n(4096)][d(1024)]
  const int NW2  = DM * DFF;      // w2_t[n(1024)][s(4096)]
  const int total = NQKV + NWO + NW1 + NW2;
  for (int idx = blockIdx.x * 256 + threadIdx.x; idx < total;
       idx += gridDim.x * 256) {
    if (idx < NQKV) {
      int n = idx >> 10, d = idx & 1023;
      int which = n >> 10, nn = n & 1023, h = nn >> 6, kk = nn & 63;
      const float* W = (which == 0) ? Wq : (which == 1) ? Wk : Wv;
      wqkv_t[idx] = f2bf(W[((h << 10) + d) * 64 + kk]);
    } else if (idx < NQKV + NWO) {
      int i = idx - NQKV;
      int n = i >> 10, d = i & 1023;
      wo_t[i] = f2bf(Wo[(d << 10) + n]);
    } else if (idx < NQKV + NWO + NW1) {
      int i = idx - NQKV - NWO;
      int n = i >> 10, d = i & 1023;           // n: 0..4095 (Dff)
      w1_t[i] = f2bf(W1[d * DFF + n]);
    } else {
      int i = idx - NQKV - NWO - NW1;
      int n = i >> 12, s = i & 4095;           // n: 0..1023, s: 0..4095
      w2_t[i] = f2bf(W2[s * DM + n]);
    }
  }
}

// ---------------------------------------------------------------------------
// GEMM: C[M,N] = A[M,K] @ Bt[N,K]^T, bf16 in / fp32 acc. m97 structure.
// ---------------------------------------------------------------------------
struct EpiArgs {
  unsigned short* q;     // EPI0
  unsigned short* k;     // EPI0
  unsigned short* vt;    // EPI0
  unsigned short* ob16;  // EPI2
  float* of32;           // EPI1 / EPI3
  const float* bias;     // EPI2 / EPI3
  const float* resid;    // EPI1
};

template <int EPI>
__global__ __launch_bounds__(256) void gemm_bt(
    const unsigned short* __restrict__ A, const unsigned short* __restrict__ Bt,
    int M, int N, int K, EpiArgs ep) {
  __shared__ __align__(16) unsigned short Als[128 * 32];
  __shared__ __align__(16) unsigned short Bls[128 * 32];
  const int t = threadIdx.x, lane = t & 63, wave = t >> 6;
  const int wm = wave >> 1, wn = wave & 1;
  const int g = lane >> 4, r16 = lane & 15;
  const int m0 = blockIdx.y * 128, n0 = blockIdx.x * 128;

  f32x4 acc[4][4];
  const f32x4 z4 = {0.f, 0.f, 0.f, 0.f};
#pragma unroll
  for (int i = 0; i < 4; ++i)
#pragma unroll
    for (int j = 0; j < 4; ++j) acc[i][j] = z4;

  for (int k0 = 0; k0 < K; k0 += 32) {
#pragma unroll
    for (int i = 0; i < 2; ++i) {
      const int cb = i * 256 + wave * 64;       // wave-uniform chunk base
      const int c = cb + lane;                  // this lane's 16B chunk
      const int row = c >> 2, cc = (c & 3) * 8; // 4 chunks per 32-elem row
      gload_lds16(A + (size_t)(m0 + row) * K + k0 + cc, &Als[cb * 8]);
      gload_lds16(Bt + (size_t)(n0 + row) * K + k0 + cc, &Bls[cb * 8]);
    }
    __syncthreads();
    bf16x8 af[4], bfr[4];
#pragma unroll
    for (int mt = 0; mt < 4; ++mt)
      af[mt] = *(const bf16x8*)&Als[(wm * 64 + mt * 16 + r16) * 32 + g * 8];
#pragma unroll
    for (int nt = 0; nt < 4; ++nt)
      bfr[nt] = *(const bf16x8*)&Bls[(wn * 64 + nt * 16 + r16) * 32 + g * 8];
#pragma unroll
    for (int mt = 0; mt < 4; ++mt)
#pragma unroll
      for (int nt = 0; nt < 4; ++nt)
        acc[mt][nt] = __builtin_amdgcn_mfma_f32_16x16x32_bf16(
            af[mt], bfr[nt], acc[mt][nt], 0, 0, 0);
    __syncthreads();
  }

  // epilogue: C row = m0+wm*64+mt*16+(lane>>4)*4+r, col = n0+wn*64+nt*16+(lane&15)
#pragma unroll
  for (int mt = 0; mt < 4; ++mt)
#pragma unroll
    for (int nt = 0; nt < 4; ++nt)
#pragma unroll
      for (int r = 0; r < 4; ++r) {
        const int row = m0 + wm * 64 + mt * 16 + g * 4 + r;
        const int col = n0 + wn * 64 + nt * 16 + r16;
        const float v = acc[mt][nt][r];
        if constexpr (EPI == 0) {  // QKV scatter; Q pre-scaled by 1/sqrt(dk)
          if (col < 1024) {
            ep.q[(size_t)row * DM + col] = f2bf(v * 0.125f);
          } else if (col < 2048) {
            ep.k[(size_t)row * DM + (col - 1024)] = f2bf(v);
          } else {
            const int c = col - 2048, hh = c >> 6, dd = c & 63;
            const int bb = row >> 11, ss = row & 2047;
            // kv bit2<->bit3 swizzle (matches attn PV contraction permutation)
            const int ssw = (ss & ~12) | ((ss & 4) << 1) | ((ss & 8) >> 1);
            ep.vt[(((size_t)bb * NH + hh) * DKH + dd) * SEQ + ssw] = f2bf(v);
          }
        } else if constexpr (EPI == 1) {  // + residual -> fp32 (x2 into d_out)
          const size_t idx = (size_t)row * N + col;
          ep.of32[idx] = v + ep.resid[idx];
        } else if constexpr (EPI == 2) {  // + bias, exact GELU -> bf16
          const float xx = v + ep.bias[col];
          const float ge = 0.5f * xx * (1.0f + erff(xx * 0.70710678118654752f));
          ep.ob16[(size_t)row * N + col] = f2bf(ge);
        } else {  // EPI 3: + bias + x2 (read d_out) -> d_out fp32
          const size_t idx = (size_t)row * N + col;
          ep.of32[idx] = ep.of32[idx] + v + ep.bias[col];
        }
      }
}

// ---------------------------------------------------------------------------
// Flash attention, swapped-operand 32x32x16 form, pipelined.
// 1D grid of 512 blocks, XCD-grouped decode: block i -> xcd k=i&7 hosts
// (b,h) groups {k, k+8, k+16, k+24}; all 16 q-blocks of a group share the XCD
// so its 512KB K/V slice stays L2-resident.
// Per 64-kv tile: issue V loads, QK^T MFMA (K from current buffer), issue
// K loads for the NEXT tile into the other buffer, softmax+pack, PV MFMA.
// ---------------------------------------------------------------------------
struct AttnState {
  f32x16 o0, o1;
  float m, lsum;
};

DEV void load_k(const unsigned short* kp, int s, bf16x8 k0[4], bf16x8 k1[4]) {
#pragma unroll
  for (int kk = 0; kk < 4; ++kk) {
    k0[kk] = *(const bf16x8*)(kp + (size_t)s * DM + kk * 16);
    k1[kk] = *(const bf16x8*)(kp + (size_t)(s + 32) * DM + kk * 16);
  }
}

DEV void attn_tile(const bf16x8 k0[4], const bf16x8 k1[4],
                   const bf16x8 v0[4], const bf16x8 v1[4],
                   const bf16x8 qf[4], AttnState& st) {
  const f32x16 z16 = {0.f};
  f32x16 pA = z16, pB = z16;
  __builtin_amdgcn_s_setprio(1);
#pragma unroll
  for (int kk = 0; kk < 4; ++kk) {
    pA = __builtin_amdgcn_mfma_f32_32x32x16_bf16(k0[kk], qf[kk], pA, 0, 0, 0);
    pB = __builtin_amdgcn_mfma_f32_32x32x16_bf16(k1[kk], qf[kk], pB, 0, 0, 0);
  }
  __builtin_amdgcn_s_setprio(0);
  // ---- online softmax, lane-local (q = lane&31); tree max ----
  float m0 = fmaxf(pA[0], pB[0]), m1 = fmaxf(pA[1], pB[1]);
  float m2 = fmaxf(pA[2], pB[2]), m3 = fmaxf(pA[3], pB[3]);
#pragma unroll
  for (int r = 4; r < 16; r += 4) {
    m0 = fmaxf(m0, fmaxf(pA[r + 0], pB[r + 0]));
    m1 = fmaxf(m1, fmaxf(pA[r + 1], pB[r + 1]));
    m2 = fmaxf(m2, fmaxf(pA[r + 2], pB[r + 2]));
    m3 = fmaxf(m3, fmaxf(pA[r + 3], pB[r + 3]));
  }
  float mx = fmaxf(fmaxf(m0, m1), fmaxf(m2, m3));
  mx = fmaxf(mx, __shfl_xor(mx, 32));
  if (__any(mx > st.m + 8.f)) {  // defer-max (T13): skip small-growth rescale
    const float mnew = fmaxf(st.m, mx);
    const float corr = __expf(st.m - mnew);
#pragma unroll
    for (int r = 0; r < 16; ++r) { st.o0[r] *= corr; st.o1[r] *= corr; }
    st.lsum *= corr;
    st.m = mnew;
  }
  float ps = 0.f;
#pragma unroll
  for (int r = 0; r < 16; ++r) {
    pA[r] = __expf(pA[r] - st.m); ps += pA[r];
    pB[r] = __expf(pB[r] - st.m); ps += pB[r];
  }
  ps += __shfl_xor(ps, 32);
  st.lsum += ps;
  // ---- pack P -> bf16 B-frags ----
  bf16x8 pw[4];
#pragma unroll
  for (int w = 0; w < 4; ++w) {
    unsigned int wd0, wd1, wd2, wd3;
    const int e0 = (w & 1) * 8;
    if (w < 2) {
      asm("v_cvt_pk_bf16_f32 %0, %1, %2" : "=v"(wd0) : "v"(pA[e0 + 0]), "v"(pA[e0 + 1]));
      asm("v_cvt_pk_bf16_f32 %0, %1, %2" : "=v"(wd1) : "v"(pA[e0 + 2]), "v"(pA[e0 + 3]));
      asm("v_cvt_pk_bf16_f32 %0, %1, %2" : "=v"(wd2) : "v"(pA[e0 + 4]), "v"(pA[e0 + 5]));
      asm("v_cvt_pk_bf16_f32 %0, %1, %2" : "=v"(wd3) : "v"(pA[e0 + 6]), "v"(pA[e0 + 7]));
    } else {
      asm("v_cvt_pk_bf16_f32 %0, %1, %2" : "=v"(wd0) : "v"(pB[e0 + 0]), "v"(pB[e0 + 1]));
      asm("v_cvt_pk_bf16_f32 %0, %1, %2" : "=v"(wd1) : "v"(pB[e0 + 2]), "v"(pB[e0 + 3]));
      asm("v_cvt_pk_bf16_f32 %0, %1, %2" : "=v"(wd2) : "v"(pB[e0 + 4]), "v"(pB[e0 + 5]));
      asm("v_cvt_pk_bf16_f32 %0, %1, %2" : "=v"(wd3) : "v"(pB[e0 + 6]), "v"(pB[e0 + 7]));
    }
    u32x4 wv = {wd0, wd1, wd2, wd3};
    pw[w] = __builtin_bit_cast(bf16x8, wv);
  }
  __builtin_amdgcn_s_setprio(1);
#pragma unroll
  for (int w = 0; w < 4; ++w) {
    st.o0 = __builtin_amdgcn_mfma_f32_32x32x16_bf16(v0[w], pw[w], st.o0, 0, 0, 0);
    st.o1 = __builtin_amdgcn_mfma_f32_32x32x16_bf16(v1[w], pw[w], st.o1, 0, 0, 0);
  }
  __builtin_amdgcn_s_setprio(0);
}

__global__ __launch_bounds__(256, 2) void attn_kernel(
    const unsigned short* __restrict__ Qc, const unsigned short* __restrict__ Kc,
    const unsigned short* __restrict__ Vt, unsigned short* __restrict__ Oc) {
  const int lane = threadIdx.x & 63, wave = threadIdx.x >> 6;
  const int hi = lane >> 5, l31 = lane & 31;
  // XCD-group decode: i&7 = XCD slot; groups {k,k+8,k+16,k+24} live on XCD k.
  const int i = blockIdx.x;
  const int k8 = i & 7, mq = i >> 3;        // mq in [0,64)
  const int grp = k8 + 8 * (mq >> 4);       // 32 (b,h) groups
  const int qb = mq & 15;                   // q-block 0..15
  const int b = grp >> 4, h = grp & 15;
  const int q0 = qb * 128 + wave * 32;
  const size_t rowbase = (size_t)b * SEQ;
  const size_t vbase = ((size_t)(b * NH + h)) * DKH * SEQ;

  // Q B-frags: lane holds q = q0+l31, dk = kk*16 + hi*8 + e  (Q pre-scaled)
  bf16x8 qf[4];
  const unsigned short* qp = Qc + (rowbase + q0 + l31) * DM + h * DKH + hi * 8;
#pragma unroll
  for (int kk = 0; kk < 4; ++kk) qf[kk] = *(const bf16x8*)(qp + kk * 16);

  AttnState st;
#pragma unroll
  for (int r = 0; r < 16; ++r) { st.o0[r] = 0.f; st.o1[r] = 0.f; }
  st.m = -1e30f; st.lsum = 0.f;

  const unsigned short* kp = Kc + (rowbase + l31) * DM + h * DKH + hi * 8;
  const unsigned short* vp = Vt + vbase + (size_t)l31 * SEQ + hi * 8;

  bf16x8 kA0[4], kA1[4], kB0[4], kB1[4];  // K double buffer (2x 32-kv halves)
  load_k(kp, 0, kA0, kA1);

  for (int s0 = 0; s0 < SEQ; s0 += 128) {
    // ===== tile t: K in bufA =====
    bf16x8 v0[4], v1[4];
#pragma unroll
    for (int w = 0; w < 4; ++w) {
      v0[w] = *(const bf16x8*)(vp + s0 + w * 16);
      v1[w] = *(const bf16x8*)(vp + (size_t)32 * SEQ + s0 + w * 16);
    }
    load_k(kp, s0 + 64, kB0, kB1);  // prefetch next tile's K
    attn_tile(kA0, kA1, v0, v1, qf, st);
    // ===== tile t+1: K in bufB =====
#pragma unroll
    for (int w = 0; w < 4; ++w) {
      v0[w] = *(const bf16x8*)(vp + s0 + 64 + w * 16);
      v1[w] = *(const bf16x8*)(vp + (size_t)32 * SEQ + s0 + 64 + w * 16);
    }
    const int snext = (s0 + 128 < SEQ) ? (s0 + 128) : 0;  // clamp (dummy ok)
    load_k(kp, snext, kA0, kA1);    // prefetch following tile's K
    attn_tile(kB0, kB1, v0, v1, qf, st);
  }

  // ---- finalize: O /= l, write bf16 (row q = l31 scalar per lane) ----
  const float inv = 1.0f / st.lsum;
  unsigned short* op = Oc + (rowbase + q0 + l31) * DM + h * DKH + hi * 4;
#pragma unroll
  for (int dblk = 0; dblk < 2; ++dblk)
#pragma unroll
    for (int g4 = 0; g4 < 4; ++g4) {  // d = dblk*32 + g4*8 + hi*4 + r
      u16x4 stv;
#pragma unroll
      for (int r = 0; r < 4; ++r) {
        const float v = (dblk ? st.o1[g4 * 4 + r] : st.o0[g4 * 4 + r]) * inv;
        stv[r] = f2bf(v);
      }
      *(u16x4*)(op + dblk * 32 + g4 * 8) = stv;
    }
}

// ---------------------------------------------------------------------------
extern "C" void kernel_launch(void* const* d_in, const int* in_sizes, int n_in,
                              void* d_out, int out_size, void* d_ws,
                              size_t ws_size, hipStream_t stream) {
  (void)in_sizes; (void)n_in; (void)out_size; (void)ws_size;
  const float* x   = (const float*)d_in[0];
  const float* Wq  = (const float*)d_in[1];
  const float* Wk  = (const float*)d_in[2];
  const float* Wv  = (const float*)d_in[3];
  const float* Wo  = (const float*)d_in[4];
  const float* W1  = (const float*)d_in[5];
  const float* b1  = (const float*)d_in[6];
  const float* W2  = (const float*)d_in[7];
  const float* b2  = (const float*)d_in[8];
  const float* g1  = (const float*)d_in[9];
  const float* be1 = (const float*)d_in[10];
  const float* g2  = (const float*)d_in[11];
  const float* be2 = (const float*)d_in[12];
  float* out = (float*)d_out;

  char* ws = (char*)d_ws;
  const size_t MB = 1024 * 1024;
  unsigned short* h_buf  = (unsigned short*)(ws + 0 * MB);
  unsigned short* wqkv_t = (unsigned short*)(ws + 8 * MB);
  unsigned short* wo_t   = (unsigned short*)(ws + 14 * MB);
  unsigned short* w1_t   = (unsigned short*)(ws + 16 * MB);
  unsigned short* w2_t   = (unsigned short*)(ws + 24 * MB);
  unsigned short* q_cat  = (unsigned short*)(ws + 32 * MB);
  unsigned short* k_cat  = (unsigned short*)(ws + 40 * MB);
  unsigned short* vt_buf = (unsigned short*)(ws + 48 * MB);
  unsigned short* ffn1   = (unsigned short*)(ws + 32 * MB);  // overlaps q/k/vt

  EpiArgs e0 = {}; e0.q = q_cat; e0.k = k_cat; e0.vt = vt_buf;
  EpiArgs e1 = {}; e1.of32 = out; e1.resid = x;
  EpiArgs e2 = {}; e2.ob16 = ffn1; e2.bias = b1;
  EpiArgs e3 = {}; e3.of32 = out; e3.bias = b2;

  convert_weights<<<12288, 256, 0, stream>>>(Wq, Wk, Wv, Wo, W1, W2,
                                             wqkv_t, wo_t, w1_t, w2_t);
  ln_kernel<<<NTOK, 256, 0, stream>>>(x, g1, be1, h_buf);
  gemm_bt<0><<<dim3(3072 / 128, NTOK / 128), 256, 0, stream>>>(
      h_buf, wqkv_t, NTOK, 3072, DM, e0);
  attn_kernel<<<512, 256, 0, stream>>>(q_cat, k_cat, vt_buf, h_buf);
  gemm_bt<1><<<dim3(DM / 128, NTOK / 128), 256, 0, stream>>>(
      h_buf, wo_t, NTOK, DM, DM, e1);
  ln_kernel<<<NTOK, 256, 0, stream>>>(out, g2, be2, h_buf);
  gemm_bt<2><<<dim3(DFF / 128, NTOK / 128), 256, 0, stream>>>(
      h_buf, w1_t, NTOK, DFF, DM, e2);
  gemm_bt<3><<<dim3(DM / 128, NTOK / 128), 256, 0, stream>>>(
      ffn1, w2_t, NTOK, DM, DFF, e3);
}

// Round 4
// 375.599 us; speedup vs baseline: 1.2064x; 1.1482x over previous
//
#include <hip/hip_runtime.h>
#include <stdint.h>

// ---------------------------------------------------------------------------
// TransformerBlock: pre-LN MHA + pre-LN FFN(GELU), bf16 MFMA internals.
// B=2 S=2048 D=1024 H=16 dk=64 Dff=4096.  GEMMs: C = A @ B^T, m97 structure.
// Attention: swapped-operand 32x32x16 MFMA flash attention, softmax fully
// in-register.  R4: Q/K/V scratch re-housed in FRAGMENT-STREAM layout
// (per 32-row block: [frag][lane][8elem]) so every attention load is a
// wave-contiguous 1KB transaction instead of a 64-line scatter (R3 showed
// loads are transaction-throughput-bound: FETCH dropped 5.5x, time flat).
// Keeps R3's K double-buffer, V-at-tile-top, setprio, XCD-group remap.
// Workspace layout (64 MB):
//   [ 0MB) h_buf   [4096,1024] bf16  (h1 -> attn_cat -> h2, serially reused)
//   [ 8MB) wqkv_t  [3072,1024] bf16
//   [14MB) wo_t    [1024,1024] bf16
//   [16MB) w1_t    [4096,1024] bf16
//   [24MB) w2_t    [1024,4096] bf16
//   [32MB) q_attn  frag-stream, 8MB   } overlapped by ffn1 [4096,4096] bf16
//   [40MB) k_attn  frag-stream, 8MB   } (dead once attention is done)
//   [48MB) v_attn  frag-stream (kv bit2<->3 folded), 8MB
// d_out doubles as x2 (attn residual) between the Wo GEMM and FFN2.
// ---------------------------------------------------------------------------

typedef __attribute__((ext_vector_type(8))) short bf16x8;
typedef __attribute__((ext_vector_type(4))) float f32x4;
typedef __attribute__((ext_vector_type(16))) float f32x16;
typedef __attribute__((ext_vector_type(4))) unsigned short u16x4;
typedef __attribute__((ext_vector_type(4))) unsigned int u32x4;

#define DEV __device__ __forceinline__

static constexpr int DM   = 1024;
static constexpr int DFF  = 4096;
static constexpr int NH   = 16;
static constexpr int DKH  = 64;
static constexpr int SEQ  = 2048;
static constexpr int NBAT = 2;
static constexpr int NTOK = NBAT * SEQ;  // 4096

DEV unsigned short f2bf(float f) {
  union { float f; unsigned int u; } v; v.f = f;
  unsigned int u = v.u;
  return (unsigned short)((u + 0x7fffu + ((u >> 16) & 1u)) >> 16);
}

DEV void gload_lds16(const unsigned short* g, unsigned short* l) {
  __builtin_amdgcn_global_load_lds(
      (const __attribute__((address_space(1))) unsigned int*)g,
      (__attribute__((address_space(3))) unsigned int*)l, 16, 0, 0);
}

// ---------------------------------------------------------------------------
// LayerNorm: x fp32 [rows,1024] -> bf16 out. One block (256 thr) per row.
// ---------------------------------------------------------------------------
__global__ __launch_bounds__(256) void ln_kernel(
    const float* __restrict__ x, const float* __restrict__ g,
    const float* __restrict__ be, unsigned short* __restrict__ out) {
  const int row = blockIdx.x;
  const int t = threadIdx.x;
  const int lane = t & 63, w = t >> 6;
  const float4* xr = (const float4*)(x + (size_t)row * DM);
  float4 v = xr[t];
  float s  = v.x + v.y + v.z + v.w;
  float s2 = v.x * v.x + v.y * v.y + v.z * v.z + v.w * v.w;
#pragma unroll
  for (int off = 32; off; off >>= 1) {
    s  += __shfl_down(s, off);
    s2 += __shfl_down(s2, off);
  }
  __shared__ float rs_[4], rq_[4];
  if (lane == 0) { rs_[w] = s; rq_[w] = s2; }
  __syncthreads();
  float fs = rs_[0] + rs_[1] + rs_[2] + rs_[3];
  float fq = rq_[0] + rq_[1] + rq_[2] + rq_[3];
  float mu = fs * (1.0f / DM);
  float var = fq * (1.0f / DM) - mu * mu;
  float rstd = rsqrtf(var + 1e-5f);
  float4 gv = ((const float4*)g)[t];
  float4 bv = ((const float4*)be)[t];
  u16x4 o;
  o[0] = f2bf((v.x - mu) * rstd * gv.x + bv.x);
  o[1] = f2bf((v.y - mu) * rstd * gv.y + bv.y);
  o[2] = f2bf((v.z - mu) * rstd * gv.z + bv.z);
  o[3] = f2bf((v.w - mu) * rstd * gv.w + bv.w);
  *(u16x4*)(out + (size_t)row * DM + t * 4) = o;
}

// ---------------------------------------------------------------------------
// Weight convert: fp32 -> bf16 B^T layouts, one flat grid-stride kernel.
// ---------------------------------------------------------------------------
__global__ __launch_bounds__(256) void convert_weights(
    const float* __restrict__ Wq, const float* __restrict__ Wk,
    const float* __restrict__ Wv, const float* __restrict__ Wo,
    const float* __restrict__ W1, const float* __restrict__ W2,
    unsigned short* __restrict__ wqkv_t, unsigned short* __restrict__ wo_t,
    unsigned short* __restrict__ w1_t, unsigned short* __restrict__ w2_t) {
  const int NQKV = 3 * DM * DM;   // wqkv_t[n(3072)][d(1024)]
  const int NWO  = DM * DM;       // wo_t[n(1024)][d(1024)]
  const int NW1  = DM * DFF;      // w1_t[n(4096)][d(1024)]
  const int NW2  = DM * DFF;      // w2_t[n(1024)][s(4096)]
  const int total = NQKV + NWO + NW1 + NW2;
  for (int idx = blockIdx.x * 256 + threadIdx.x; idx < total;
       idx += gridDim.x * 256) {
    if (idx < NQKV) {
      int n = idx >> 10, d = idx & 1023;
      int which = n >> 10, nn = n & 1023, h = nn >> 6, kk = nn & 63;
      const float* W = (which == 0) ? Wq : (which == 1) ? Wk : Wv;
      wqkv_t[idx] = f2bf(W[((h << 10) + d) * 64 + kk]);
    } else if (idx < NQKV + NWO) {
      int i = idx - NQKV;
      int n = i >> 10, d = i & 1023;
      wo_t[i] = f2bf(Wo[(d << 10) + n]);
    } else if (idx < NQKV + NWO + NW1) {
      int i = idx - NQKV - NWO;
      int n = i >> 10, d = i & 1023;           // n: 0..4095 (Dff)
      w1_t[i] = f2bf(W1[d * DFF + n]);
    } else {
      int i = idx - NQKV - NWO - NW1;
      int n = i >> 12, s = i & 4095;           // n: 0..1023, s: 0..4095
      w2_t[i] = f2bf(W2[s * DM + n]);
    }
  }
}

// ---------------------------------------------------------------------------
// GEMM: C[M,N] = A[M,K] @ Bt[N,K]^T, bf16 in / fp32 acc. m97 structure.
// ---------------------------------------------------------------------------
struct EpiArgs {
  unsigned short* q;     // EPI0 (frag-stream)
  unsigned short* k;     // EPI0 (frag-stream)
  unsigned short* vt;    // EPI0 (frag-stream, kv bit2<->3 folded)
  unsigned short* ob16;  // EPI2
  float* of32;           // EPI1 / EPI3
  const float* bias;     // EPI2 / EPI3
  const float* resid;    // EPI1
};

template <int EPI>
__global__ __launch_bounds__(256) void gemm_bt(
    const unsigned short* __restrict__ A, const unsigned short* __restrict__ Bt,
    int M, int N, int K, EpiArgs ep) {
  __shared__ __align__(16) unsigned short Als[128 * 32];
  __shared__ __align__(16) unsigned short Bls[128 * 32];
  const int t = threadIdx.x, lane = t & 63, wave = t >> 6;
  const int wm = wave >> 1, wn = wave & 1;
  const int g = lane >> 4, r16 = lane & 15;
  const int m0 = blockIdx.y * 128, n0 = blockIdx.x * 128;

  f32x4 acc[4][4];
  const f32x4 z4 = {0.f, 0.f, 0.f, 0.f};
#pragma unroll
  for (int i = 0; i < 4; ++i)
#pragma unroll
    for (int j = 0; j < 4; ++j) acc[i][j] = z4;

  for (int k0 = 0; k0 < K; k0 += 32) {
#pragma unroll
    for (int i = 0; i < 2; ++i) {
      const int cb = i * 256 + wave * 64;       // wave-uniform chunk base
      const int c = cb + lane;                  // this lane's 16B chunk
      const int row = c >> 2, cc = (c & 3) * 8; // 4 chunks per 32-elem row
      gload_lds16(A + (size_t)(m0 + row) * K + k0 + cc, &Als[cb * 8]);
      gload_lds16(Bt + (size_t)(n0 + row) * K + k0 + cc, &Bls[cb * 8]);
    }
    __syncthreads();
    bf16x8 af[4], bfr[4];
#pragma unroll
    for (int mt = 0; mt < 4; ++mt)
      af[mt] = *(const bf16x8*)&Als[(wm * 64 + mt * 16 + r16) * 32 + g * 8];
#pragma unroll
    for (int nt = 0; nt < 4; ++nt)
      bfr[nt] = *(const bf16x8*)&Bls[(wn * 64 + nt * 16 + r16) * 32 + g * 8];
#pragma unroll
    for (int mt = 0; mt < 4; ++mt)
#pragma unroll
      for (int nt = 0; nt < 4; ++nt)
        acc[mt][nt] = __builtin_amdgcn_mfma_f32_16x16x32_bf16(
            af[mt], bfr[nt], acc[mt][nt], 0, 0, 0);
    __syncthreads();
  }

  // epilogue: C row = m0+wm*64+mt*16+(lane>>4)*4+r, col = n0+wn*64+nt*16+(lane&15)
#pragma unroll
  for (int mt = 0; mt < 4; ++mt)
#pragma unroll
    for (int nt = 0; nt < 4; ++nt)
#pragma unroll
      for (int r = 0; r < 4; ++r) {
        const int row = m0 + wm * 64 + mt * 16 + g * 4 + r;
        const int col = n0 + wn * 64 + nt * 16 + r16;
        const float v = acc[mt][nt][r];
        if constexpr (EPI == 0) {  // QKV -> fragment-stream scratch layouts
          const int bb = row >> 11, rr = row & 2047;
          if (col < 1024) {        // Q (pre-scaled by 1/sqrt(dk))
            const int hh = col >> 6, dk = col & 63;
            const int kk = dk >> 4, h8 = (dk >> 3) & 1, e = dk & 7;
            const int qblk = rr >> 5, l31 = rr & 31;
            ep.q[((size_t)(bb * NH + hh) * 64 + qblk) * 2048 + kk * 512 +
                 (h8 * 32 + l31) * 8 + e] = f2bf(v * 0.125f);
          } else if (col < 2048) { // K
            const int c = col - 1024;
            const int hh = c >> 6, dk = c & 63;
            const int kk = dk >> 4, h8 = (dk >> 3) & 1, e = dk & 7;
            const int kvblk = rr >> 5, l31 = rr & 31;
            ep.k[((size_t)(bb * NH + hh) * 64 + kvblk) * 2048 + kk * 512 +
                 (h8 * 32 + l31) * 8 + e] = f2bf(v);
          } else {                 // V (kv bit2<->3 swizzle folded in)
            const int c = col - 2048, hh = c >> 6, dd = c & 63;
            const int ssw = (rr & ~12) | ((rr & 4) << 1) | ((rr & 8) >> 1);
            const int t64 = ssw >> 6, w = (ssw >> 4) & 3;
            const int h8 = (ssw >> 3) & 1, e = ssw & 7;
            const int dblk = dd >> 5, l31 = dd & 31;
            ep.vt[(((size_t)(bb * NH + hh) * 32 + t64) * 8 + dblk * 4 + w) * 512 +
                  (h8 * 32 + l31) * 8 + e] = f2bf(v);
          }
        } else if constexpr (EPI == 1) {  // + residual -> fp32 (x2 into d_out)
          const size_t idx = (size_t)row * N + col;
          ep.of32[idx] = v + ep.resid[idx];
        } else if constexpr (EPI == 2) {  // + bias, exact GELU -> bf16
          const float xx = v + ep.bias[col];
          const float ge = 0.5f * xx * (1.0f + erff(xx * 0.70710678118654752f));
          ep.ob16[(size_t)row * N + col] = f2bf(ge);
        } else {  // EPI 3: + bias + x2 (read d_out) -> d_out fp32
          const size_t idx = (size_t)row * N + col;
          ep.of32[idx] = ep.of32[idx] + v + ep.bias[col];
        }
      }
}

// ---------------------------------------------------------------------------
// Flash attention, swapped-operand 32x32x16 form, pipelined, frag-stream I/O.
// 1D grid of 512 blocks, XCD-grouped decode (all 16 q-blocks of a (b,h) on
// one XCD).  All Q/K/V loads are wave-contiguous 1KB (lane*8 within stream).
// ---------------------------------------------------------------------------
struct AttnState {
  f32x16 o0, o1;
  float m, lsum;
};

DEV void load_k(const unsigned short* kbase, int s, bf16x8 k0[4], bf16x8 k1[4]) {
  const unsigned short* p = kbase + (size_t)(s >> 5) * 2048;
#pragma unroll
  for (int kk = 0; kk < 4; ++kk) {
    k0[kk] = *(const bf16x8*)(p + kk * 512);
    k1[kk] = *(const bf16x8*)(p + 2048 + kk * 512);
  }
}

DEV void attn_tile(const bf16x8 k0[4], const bf16x8 k1[4],
                   const bf16x8 v0[4], const bf16x8 v1[4],
                   const bf16x8 qf[4], AttnState& st) {
  const f32x16 z16 = {0.f};
  f32x16 pA = z16, pB = z16;
  __builtin_amdgcn_s_setprio(1);
#pragma unroll
  for (int kk = 0; kk < 4; ++kk) {
    pA = __builtin_amdgcn_mfma_f32_32x32x16_bf16(k0[kk], qf[kk], pA, 0, 0, 0);
    pB = __builtin_amdgcn_mfma_f32_32x32x16_bf16(k1[kk], qf[kk], pB, 0, 0, 0);
  }
  __builtin_amdgcn_s_setprio(0);
  // ---- online softmax, lane-local (q = lane&31); tree max ----
  float m0 = fmaxf(pA[0], pB[0]), m1 = fmaxf(pA[1], pB[1]);
  float m2 = fmaxf(pA[2], pB[2]), m3 = fmaxf(pA[3], pB[3]);
#pragma unroll
  for (int r = 4; r < 16; r += 4) {
    m0 = fmaxf(m0, fmaxf(pA[r + 0], pB[r + 0]));
    m1 = fmaxf(m1, fmaxf(pA[r + 1], pB[r + 1]));
    m2 = fmaxf(m2, fmaxf(pA[r + 2], pB[r + 2]));
    m3 = fmaxf(m3, fmaxf(pA[r + 3], pB[r + 3]));
  }
  float mx = fmaxf(fmaxf(m0, m1), fmaxf(m2, m3));
  mx = fmaxf(mx, __shfl_xor(mx, 32));
  if (__any(mx > st.m + 8.f)) {  // defer-max (T13): skip small-growth rescale
    const float mnew = fmaxf(st.m, mx);
    const float corr = __expf(st.m - mnew);
#pragma unroll
    for (int r = 0; r < 16; ++r) { st.o0[r] *= corr; st.o1[r] *= corr; }
    st.lsum *= corr;
    st.m = mnew;
  }
  float ps = 0.f;
#pragma unroll
  for (int r = 0; r < 16; ++r) {
    pA[r] = __expf(pA[r] - st.m); ps += pA[r];
    pB[r] = __expf(pB[r] - st.m); ps += pB[r];
  }
  ps += __shfl_xor(ps, 32);
  st.lsum += ps;
  // ---- pack P -> bf16 B-frags ----
  bf16x8 pw[4];
#pragma unroll
  for (int w = 0; w < 4; ++w) {
    unsigned int wd0, wd1, wd2, wd3;
    const int e0 = (w & 1) * 8;
    if (w < 2) {
      asm("v_cvt_pk_bf16_f32 %0, %1, %2" : "=v"(wd0) : "v"(pA[e0 + 0]), "v"(pA[e0 + 1]));
      asm("v_cvt_pk_bf16_f32 %0, %1, %2" : "=v"(wd1) : "v"(pA[e0 + 2]), "v"(pA[e0 + 3]));
      asm("v_cvt_pk_bf16_f32 %0, %1, %2" : "=v"(wd2) : "v"(pA[e0 + 4]), "v"(pA[e0 + 5]));
      asm("v_cvt_pk_bf16_f32 %0, %1, %2" : "=v"(wd3) : "v"(pA[e0 + 6]), "v"(pA[e0 + 7]));
    } else {
      asm("v_cvt_pk_bf16_f32 %0, %1, %2" : "=v"(wd0) : "v"(pB[e0 + 0]), "v"(pB[e0 + 1]));
      asm("v_cvt_pk_bf16_f32 %0, %1, %2" : "=v"(wd1) : "v"(pB[e0 + 2]), "v"(pB[e0 + 3]));
      asm("v_cvt_pk_bf16_f32 %0, %1, %2" : "=v"(wd2) : "v"(pB[e0 + 4]), "v"(pB[e0 + 5]));
      asm("v_cvt_pk_bf16_f32 %0, %1, %2" : "=v"(wd3) : "v"(pB[e0 + 6]), "v"(pB[e0 + 7]));
    }
    u32x4 wv = {wd0, wd1, wd2, wd3};
    pw[w] = __builtin_bit_cast(bf16x8, wv);
  }
  __builtin_amdgcn_s_setprio(1);
#pragma unroll
  for (int w = 0; w < 4; ++w) {
    st.o0 = __builtin_amdgcn_mfma_f32_32x32x16_bf16(v0[w], pw[w], st.o0, 0, 0, 0);
    st.o1 = __builtin_amdgcn_mfma_f32_32x32x16_bf16(v1[w], pw[w], st.o1, 0, 0, 0);
  }
  __builtin_amdgcn_s_setprio(0);
}

__global__ __launch_bounds__(256, 2) void attn_kernel(
    const unsigned short* __restrict__ Qc, const unsigned short* __restrict__ Kc,
    const unsigned short* __restrict__ Vt, unsigned short* __restrict__ Oc) {
  const int lane = threadIdx.x & 63, wave = threadIdx.x >> 6;
  const int hi = lane >> 5, l31 = lane & 31;
  // XCD-group decode: i&7 = XCD slot; groups {k,k+8,k+16,k+24} live on XCD k.
  const int i = blockIdx.x;
  const int k8 = i & 7, mq = i >> 3;        // mq in [0,64)
  const int grp = k8 + 8 * (mq >> 4);       // 32 (b,h) groups
  const int qb = mq & 15;                   // q-block 0..15
  const int b = grp >> 4, h = grp & 15;
  const int q0 = qb * 128 + wave * 32;

  // frag-stream base pointers (all loads: base + frag*512 + lane*8)
  const unsigned short* qbp = Qc + ((size_t)grp * 64 + (q0 >> 5)) * 2048 + lane * 8;
  const unsigned short* kbp = Kc + (size_t)grp * 64 * 2048 + lane * 8;
  const unsigned short* vbp = Vt + (size_t)grp * 32 * 4096 + lane * 8;

  bf16x8 qf[4];
#pragma unroll
  for (int kk = 0; kk < 4; ++kk) qf[kk] = *(const bf16x8*)(qbp + kk * 512);

  AttnState st;
#pragma unroll
  for (int r = 0; r < 16; ++r) { st.o0[r] = 0.f; st.o1[r] = 0.f; }
  st.m = -1e30f; st.lsum = 0.f;

  bf16x8 kA0[4], kA1[4], kB0[4], kB1[4];  // K double buffer (2x 32-kv halves)
  load_k(kbp, 0, kA0, kA1);

  for (int s0 = 0; s0 < SEQ; s0 += 128) {
    // ===== tile t: K in bufA =====
    const unsigned short* vt0 = vbp + (size_t)(s0 >> 6) * 4096;
    bf16x8 v0[4], v1[4];
#pragma unroll
    for (int w = 0; w < 4; ++w) {
      v0[w] = *(const bf16x8*)(vt0 + w * 512);         // dblk 0
      v1[w] = *(const bf16x8*)(vt0 + 2048 + w * 512);  // dblk 1
    }
    load_k(kbp, s0 + 64, kB0, kB1);  // prefetch next tile's K
    attn_tile(kA0, kA1, v0, v1, qf, st);
    // ===== tile t+1: K in bufB =====
    const unsigned short* vt1 = vbp + (size_t)((s0 + 64) >> 6) * 4096;
#pragma unroll
    for (int w = 0; w < 4; ++w) {
      v0[w] = *(const bf16x8*)(vt1 + w * 512);
      v1[w] = *(const bf16x8*)(vt1 + 2048 + w * 512);
    }
    const int snext = (s0 + 128 < SEQ) ? (s0 + 128) : 0;  // clamp (dummy ok)
    load_k(kbp, snext, kA0, kA1);    // prefetch following tile's K
    attn_tile(kB0, kB1, v0, v1, qf, st);
  }

  // ---- finalize: O /= l, write bf16 (row q = l31 scalar per lane) ----
  const float inv = 1.0f / st.lsum;
  const size_t rowbase = (size_t)b * SEQ;
  unsigned short* op = Oc + (rowbase + q0 + l31) * DM + h * DKH + hi * 4;
#pragma unroll
  for (int dblk = 0; dblk < 2; ++dblk)
#pragma unroll
    for (int g4 = 0; g4 < 4; ++g4) {  // d = dblk*32 + g4*8 + hi*4 + r
      u16x4 stv;
#pragma unroll
      for (int r = 0; r < 4; ++r) {
        const float v = (dblk ? st.o1[g4 * 4 + r] : st.o0[g4 * 4 + r]) * inv;
        stv[r] = f2bf(v);
      }
      *(u16x4*)(op + dblk * 32 + g4 * 8) = stv;
    }
}

// ---------------------------------------------------------------------------
extern "C" void kernel_launch(void* const* d_in, const int* in_sizes, int n_in,
                              void* d_out, int out_size, void* d_ws,
                              size_t ws_size, hipStream_t stream) {
  (void)in_sizes; (void)n_in; (void)out_size; (void)ws_size;
  const float* x   = (const float*)d_in[0];
  const float* Wq  = (const float*)d_in[1];
  const float* Wk  = (const float*)d_in[2];
  const float* Wv  = (const float*)d_in[3];
  const float* Wo  = (const float*)d_in[4];
  const float* W1  = (const float*)d_in[5];
  const float* b1  = (const float*)d_in[6];
  const float* W2  = (const float*)d_in[7];
  const float* b2  = (const float*)d_in[8];
  const float* g1  = (const float*)d_in[9];
  const float* be1 = (const float*)d_in[10];
  const float* g2  = (const float*)d_in[11];
  const float* be2 = (const float*)d_in[12];
  float* out = (float*)d_out;

  char* ws = (char*)d_ws;
  const size_t MB = 1024 * 1024;
  unsigned short* h_buf  = (unsigned short*)(ws + 0 * MB);
  unsigned short* wqkv_t = (unsigned short*)(ws + 8 * MB);
  unsigned short* wo_t   = (unsigned short*)(ws + 14 * MB);
  unsigned short* w1_t   = (unsigned short*)(ws + 16 * MB);
  unsigned short* w2_t   = (unsigned short*)(ws + 24 * MB);
  unsigned short* q_attn = (unsigned short*)(ws + 32 * MB);
  unsigned short* k_attn = (unsigned short*)(ws + 40 * MB);
  unsigned short* v_attn = (unsigned short*)(ws + 48 * MB);
  unsigned short* ffn1   = (unsigned short*)(ws + 32 * MB);  // overlaps q/k/v

  EpiArgs e0 = {}; e0.q = q_attn; e0.k = k_attn; e0.vt = v_attn;
  EpiArgs e1 = {}; e1.of32 = out; e1.resid = x;
  EpiArgs e2 = {}; e2.ob16 = ffn1; e2.bias = b1;
  EpiArgs e3 = {}; e3.of32 = out; e3.bias = b2;

  convert_weights<<<12288, 256, 0, stream>>>(Wq, Wk, Wv, Wo, W1, W2,
                                             wqkv_t, wo_t, w1_t, w2_t);
  ln_kernel<<<NTOK, 256, 0, stream>>>(x, g1, be1, h_buf);
  gemm_bt<0><<<dim3(3072 / 128, NTOK / 128), 256, 0, stream>>>(
      h_buf, wqkv_t, NTOK, 3072, DM, e0);
  attn_kernel<<<512, 256, 0, stream>>>(q_attn, k_attn, v_attn, h_buf);
  gemm_bt<1><<<dim3(DM / 128, NTOK / 128), 256, 0, stream>>>(
      h_buf, wo_t, NTOK, DM, DM, e1);
  ln_kernel<<<NTOK, 256, 0, stream>>>(out, g2, be2, h_buf);
  gemm_bt<2><<<dim3(DFF / 128, NTOK / 128), 256, 0, stream>>>(
      h_buf, w1_t, NTOK, DFF, DM, e2);
  gemm_bt<3><<<dim3(DM / 128, NTOK / 128), 256, 0, stream>>>(
      ffn1, w2_t, NTOK, DM, DFF, e3);
}

// Round 5
// 316.326 us; speedup vs baseline: 1.4325x; 1.1874x over previous
//
#include <hip/hip_runtime.h>
#include <stdint.h>

// ---------------------------------------------------------------------------
// TransformerBlock: pre-LN MHA + pre-LN FFN(GELU), bf16 MFMA internals.
// B=2 S=2048 D=1024 H=16 dk=64 Dff=4096.
// R5: (a) FFN2 split-K=2 + explicit 2-phase double-buffered GEMM (T3 minimum
// recipe) -> 2 blocks/CU and prefetch-hidden staging (was 1 blk/CU, 12.9%
// MfmaUtil, barrier-stall-bound); deterministic fp32 partial + reduce pass.
// (b) Wo on the same pipelined kernel (no split). (c) XOR chunk-swizzle on
// all GEMM LDS staging/reads (both-sides involution) -> bank conflicts
// 4.2M -> ~0.  Attention unchanged from R4 (frag-stream, ~73us).
// Workspace layout (64 MB):
//   [ 0MB) h_buf [4096,1024]bf16 (h1/attn/h2)   } 0-16MB dead at FFN2 time ->
//   [ 8MB) wqkv_t[3072,1024]bf16                }   p0 fp32 partial (16MB)
//   [14MB) wo_t  [1024,1024]bf16                }
//   [16MB) w1_t  [4096,1024]bf16
//   [24MB) w2_t  [1024,4096]bf16
//   [32MB) q_attn frag-stream 8MB   } overlapped by ffn1 [4096,4096] bf16
//   [40MB) k_attn frag-stream 8MB   }
//   [48MB) v_attn frag-stream 8MB
// d_out doubles as x2 (attn residual) between the Wo GEMM and FFN2.
// ---------------------------------------------------------------------------

typedef __attribute__((ext_vector_type(8))) short bf16x8;
typedef __attribute__((ext_vector_type(4))) float f32x4;
typedef __attribute__((ext_vector_type(16))) float f32x16;
typedef __attribute__((ext_vector_type(4))) unsigned short u16x4;
typedef __attribute__((ext_vector_type(4))) unsigned int u32x4;

#define DEV __device__ __forceinline__

static constexpr int DM   = 1024;
static constexpr int DFF  = 4096;
static constexpr int NH   = 16;
static constexpr int DKH  = 64;
static constexpr int SEQ  = 2048;
static constexpr int NBAT = 2;
static constexpr int NTOK = NBAT * SEQ;  // 4096

DEV unsigned short f2bf(float f) {
  union { float f; unsigned int u; } v; v.f = f;
  unsigned int u = v.u;
  return (unsigned short)((u + 0x7fffu + ((u >> 16) & 1u)) >> 16);
}

DEV void gload_lds16(const unsigned short* g, unsigned short* l) {
  __builtin_amdgcn_global_load_lds(
      (const __attribute__((address_space(1))) unsigned int*)g,
      (__attribute__((address_space(3))) unsigned int*)l, 16, 0, 0);
}

// ---------------------------------------------------------------------------
// LayerNorm: x fp32 [rows,1024] -> bf16 out. One block (256 thr) per row.
// ---------------------------------------------------------------------------
__global__ __launch_bounds__(256) void ln_kernel(
    const float* __restrict__ x, const float* __restrict__ g,
    const float* __restrict__ be, unsigned short* __restrict__ out) {
  const int row = blockIdx.x;
  const int t = threadIdx.x;
  const int lane = t & 63, w = t >> 6;
  const float4* xr = (const float4*)(x + (size_t)row * DM);
  float4 v = xr[t];
  float s  = v.x + v.y + v.z + v.w;
  float s2 = v.x * v.x + v.y * v.y + v.z * v.z + v.w * v.w;
#pragma unroll
  for (int off = 32; off; off >>= 1) {
    s  += __shfl_down(s, off);
    s2 += __shfl_down(s2, off);
  }
  __shared__ float rs_[4], rq_[4];
  if (lane == 0) { rs_[w] = s; rq_[w] = s2; }
  __syncthreads();
  float fs = rs_[0] + rs_[1] + rs_[2] + rs_[3];
  float fq = rq_[0] + rq_[1] + rq_[2] + rq_[3];
  float mu = fs * (1.0f / DM);
  float var = fq * (1.0f / DM) - mu * mu;
  float rstd = rsqrtf(var + 1e-5f);
  float4 gv = ((const float4*)g)[t];
  float4 bv = ((const float4*)be)[t];
  u16x4 o;
  o[0] = f2bf((v.x - mu) * rstd * gv.x + bv.x);
  o[1] = f2bf((v.y - mu) * rstd * gv.y + bv.y);
  o[2] = f2bf((v.z - mu) * rstd * gv.z + bv.z);
  o[3] = f2bf((v.w - mu) * rstd * gv.w + bv.w);
  *(u16x4*)(out + (size_t)row * DM + t * 4) = o;
}

// ---------------------------------------------------------------------------
// Weight convert: fp32 -> bf16 B^T layouts, one flat grid-stride kernel.
// ---------------------------------------------------------------------------
__global__ __launch_bounds__(256) void convert_weights(
    const float* __restrict__ Wq, const float* __restrict__ Wk,
    const float* __restrict__ Wv, const float* __restrict__ Wo,
    const float* __restrict__ W1, const float* __restrict__ W2,
    unsigned short* __restrict__ wqkv_t, unsigned short* __restrict__ wo_t,
    unsigned short* __restrict__ w1_t, unsigned short* __restrict__ w2_t) {
  const int NQKV = 3 * DM * DM;
  const int NWO  = DM * DM;
  const int NW1  = DM * DFF;
  const int NW2  = DM * DFF;
  const int total = NQKV + NWO + NW1 + NW2;
  for (int idx = blockIdx.x * 256 + threadIdx.x; idx < total;
       idx += gridDim.x * 256) {
    if (idx < NQKV) {
      int n = idx >> 10, d = idx & 1023;
      int which = n >> 10, nn = n & 1023, h = nn >> 6, kk = nn & 63;
      const float* W = (which == 0) ? Wq : (which == 1) ? Wk : Wv;
      wqkv_t[idx] = f2bf(W[((h << 10) + d) * 64 + kk]);
    } else if (idx < NQKV + NWO) {
      int i = idx - NQKV;
      int n = i >> 10, d = i & 1023;
      wo_t[i] = f2bf(Wo[(d << 10) + n]);
    } else if (idx < NQKV + NWO + NW1) {
      int i = idx - NQKV - NWO;
      int n = i >> 10, d = i & 1023;           // n: 0..4095 (Dff)
      w1_t[i] = f2bf(W1[d * DFF + n]);
    } else {
      int i = idx - NQKV - NWO - NW1;
      int n = i >> 12, s = i & 4095;           // n: 0..1023, s: 0..4095
      w2_t[i] = f2bf(W2[s * DM + n]);
    }
  }
}

// ---------------------------------------------------------------------------
struct EpiArgs {
  unsigned short* q;     // EPI0 (frag-stream)
  unsigned short* k;     // EPI0 (frag-stream)
  unsigned short* vt;    // EPI0 (frag-stream, kv bit2<->3 folded)
  unsigned short* ob16;  // EPI2
  float* of32;           // EPI1 / EPI3 / EPI4(z=1)
  float* p0;             // EPI4(z=0) fp32 partial
  const float* bias;     // EPI2 / EPI4
  const float* resid;    // EPI1
};

template <int EPI>
DEV void epilogue_elem(float v, int row, int col, int N, int bz,
                       const EpiArgs& ep) {
  if constexpr (EPI == 0) {  // QKV -> fragment-stream scratch layouts
    const int bb = row >> 11, rr = row & 2047;
    if (col < 1024) {        // Q (pre-scaled by 1/sqrt(dk))
      const int hh = col >> 6, dk = col & 63;
      const int kk = dk >> 4, h8 = (dk >> 3) & 1, e = dk & 7;
      const int qblk = rr >> 5, l31 = rr & 31;
      ep.q[((size_t)(bb * NH + hh) * 64 + qblk) * 2048 + kk * 512 +
           (h8 * 32 + l31) * 8 + e] = f2bf(v * 0.125f);
    } else if (col < 2048) { // K
      const int c = col - 1024;
      const int hh = c >> 6, dk = c & 63;
      const int kk = dk >> 4, h8 = (dk >> 3) & 1, e = dk & 7;
      const int kvblk = rr >> 5, l31 = rr & 31;
      ep.k[((size_t)(bb * NH + hh) * 64 + kvblk) * 2048 + kk * 512 +
           (h8 * 32 + l31) * 8 + e] = f2bf(v);
    } else {                 // V (kv bit2<->3 swizzle folded in)
      const int c = col - 2048, hh = c >> 6, dd = c & 63;
      const int ssw = (rr & ~12) | ((rr & 4) << 1) | ((rr & 8) >> 1);
      const int t64 = ssw >> 6, w = (ssw >> 4) & 3;
      const int h8 = (ssw >> 3) & 1, e = ssw & 7;
      const int dblk = dd >> 5, l31 = dd & 31;
      ep.vt[(((size_t)(bb * NH + hh) * 32 + t64) * 8 + dblk * 4 + w) * 512 +
            (h8 * 32 + l31) * 8 + e] = f2bf(v);
    }
  } else if constexpr (EPI == 1) {  // + residual -> fp32 (x2 into d_out)
    const size_t idx = (size_t)row * N + col;
    ep.of32[idx] = v + ep.resid[idx];
  } else if constexpr (EPI == 2) {  // + bias, exact GELU -> bf16
    const float xx = v + ep.bias[col];
    const float ge = 0.5f * xx * (1.0f + erff(xx * 0.70710678118654752f));
    ep.ob16[(size_t)row * N + col] = f2bf(ge);
  } else {  // EPI 4: FFN2 split-K. z=0 -> fp32 partial; z=1 -> out += v+bias
    const size_t idx = (size_t)row * N + col;
    if (bz == 0) ep.p0[idx] = v;
    else ep.of32[idx] = ep.of32[idx] + v + ep.bias[col];
  }
}

// ---------------------------------------------------------------------------
// GEMM (m97 structure, BK=32, single-buffered): for grids >= 2-3 blocks/CU.
// LDS chunk XOR-swizzle: position p in row holds global chunk p^((row>>1)&3).
// ---------------------------------------------------------------------------
template <int EPI>
__global__ __launch_bounds__(256) void gemm_bt(
    const unsigned short* __restrict__ A, const unsigned short* __restrict__ Bt,
    int M, int N, int K, EpiArgs ep) {
  __shared__ __align__(16) unsigned short Als[128 * 32];
  __shared__ __align__(16) unsigned short Bls[128 * 32];
  const int t = threadIdx.x, lane = t & 63, wave = t >> 6;
  const int wm = wave >> 1, wn = wave & 1;
  const int g = lane >> 4, r16 = lane & 15;
  const int m0 = blockIdx.y * 128, n0 = blockIdx.x * 128;
  const int rsw = (r16 >> 1) & 3;

  f32x4 acc[4][4];
  const f32x4 z4 = {0.f, 0.f, 0.f, 0.f};
#pragma unroll
  for (int i = 0; i < 4; ++i)
#pragma unroll
    for (int j = 0; j < 4; ++j) acc[i][j] = z4;

  for (int k0 = 0; k0 < K; k0 += 32) {
#pragma unroll
    for (int i = 0; i < 2; ++i) {
      const int cb = i * 256 + wave * 64;       // wave-uniform chunk base
      const int c = cb + lane;
      const int row = c >> 2;
      const int sc = ((c & 3) ^ ((row >> 1) & 3)) * 8;  // src-chunk swizzle
      gload_lds16(A + (size_t)(m0 + row) * K + k0 + sc, &Als[cb * 8]);
      gload_lds16(Bt + (size_t)(n0 + row) * K + k0 + sc, &Bls[cb * 8]);
    }
    __syncthreads();
    bf16x8 af[4], bfr[4];
#pragma unroll
    for (int mt = 0; mt < 4; ++mt)
      af[mt] = *(const bf16x8*)&Als[(wm * 64 + mt * 16 + r16) * 32 + (g ^ rsw) * 8];
#pragma unroll
    for (int nt = 0; nt < 4; ++nt)
      bfr[nt] = *(const bf16x8*)&Bls[(wn * 64 + nt * 16 + r16) * 32 + (g ^ rsw) * 8];
#pragma unroll
    for (int mt = 0; mt < 4; ++mt)
#pragma unroll
      for (int nt = 0; nt < 4; ++nt)
        acc[mt][nt] = __builtin_amdgcn_mfma_f32_16x16x32_bf16(
            af[mt], bfr[nt], acc[mt][nt], 0, 0, 0);
    __syncthreads();
  }
#pragma unroll
  for (int mt = 0; mt < 4; ++mt)
#pragma unroll
    for (int nt = 0; nt < 4; ++nt)
#pragma unroll
      for (int r = 0; r < 4; ++r)
        epilogue_elem<EPI>(acc[mt][nt][r], m0 + wm * 64 + mt * 16 + g * 4 + r,
                           n0 + wn * 64 + nt * 16 + r16, N, 0, ep);
}

// ---------------------------------------------------------------------------
// Pipelined GEMM (2-phase, BK=64, explicit LDS double buffer): for 1 blk/CU
// grids (Wo, FFN2).  Prefetch tile t+1 BEFORE computing tile t so the
// __syncthreads vmcnt-drain is short.  Kc = per-chunk K; ldk = row stride;
// blockIdx.z = K-chunk (split-K).  Chunk swizzle: p^(row&7) over 8 chunks.
// ---------------------------------------------------------------------------
template <int EPI>
__global__ __launch_bounds__(256) void gemm_pipe(
    const unsigned short* __restrict__ A, const unsigned short* __restrict__ Bt,
    int N, int Kc, int ldk, EpiArgs ep) {
  __shared__ __align__(16) unsigned short Als[2][128 * 64];
  __shared__ __align__(16) unsigned short Bls[2][128 * 64];
  const int t = threadIdx.x, lane = t & 63, wave = t >> 6;
  const int wm = wave >> 1, wn = wave & 1;
  const int g = lane >> 4, r16 = lane & 15;
  const int m0 = blockIdx.y * 128, n0 = blockIdx.x * 128;
  const int kbase = blockIdx.z * Kc;

  f32x4 acc[4][4];
  const f32x4 z4 = {0.f, 0.f, 0.f, 0.f};
#pragma unroll
  for (int i = 0; i < 4; ++i)
#pragma unroll
    for (int j = 0; j < 4; ++j) acc[i][j] = z4;

  auto stage = [&](int b, int k0) {
#pragma unroll
    for (int i = 0; i < 4; ++i) {
      const int cb = i * 256 + wave * 64;       // wave-uniform chunk base
      const int c = cb + lane;
      const int row = c >> 3;
      const int sc = ((c & 7) ^ (row & 7)) * 8; // src-chunk swizzle (8 chunks)
      gload_lds16(A + (size_t)(m0 + row) * ldk + kbase + k0 + sc, &Als[b][cb * 8]);
      gload_lds16(Bt + (size_t)(n0 + row) * ldk + kbase + k0 + sc, &Bls[b][cb * 8]);
    }
  };

  const int NT = Kc >> 6;
  stage(0, 0);
  __syncthreads();
  for (int kt = 0; kt < NT; ++kt) {
    const int cur = kt & 1;
    if (kt + 1 < NT) stage(cur ^ 1, (kt + 1) << 6);  // prefetch next tile
    const int sw = r16 & 7;
    bf16x8 af[2][4], bfr[2][4];
#pragma unroll
    for (int ks = 0; ks < 2; ++ks) {
#pragma unroll
      for (int mt = 0; mt < 4; ++mt)
        af[ks][mt] = *(const bf16x8*)&Als[cur][(wm * 64 + mt * 16 + r16) * 64 +
                                              (((ks << 2) | g) ^ sw) * 8];
#pragma unroll
      for (int nt = 0; nt < 4; ++nt)
        bfr[ks][nt] = *(const bf16x8*)&Bls[cur][(wn * 64 + nt * 16 + r16) * 64 +
                                               (((ks << 2) | g) ^ sw) * 8];
    }
    __builtin_amdgcn_s_setprio(1);
#pragma unroll
    for (int ks = 0; ks < 2; ++ks)
#pragma unroll
      for (int mt = 0; mt < 4; ++mt)
#pragma unroll
        for (int nt = 0; nt < 4; ++nt)
          acc[mt][nt] = __builtin_amdgcn_mfma_f32_16x16x32_bf16(
              af[ks][mt], bfr[ks][nt], acc[mt][nt], 0, 0, 0);
    __builtin_amdgcn_s_setprio(0);
    __syncthreads();  // drains prefetch vmcnt (already ~landed) + LDS reuse
  }
#pragma unroll
  for (int mt = 0; mt < 4; ++mt)
#pragma unroll
    for (int nt = 0; nt < 4; ++nt)
#pragma unroll
      for (int r = 0; r < 4; ++r)
        epilogue_elem<EPI>(acc[mt][nt][r], m0 + wm * 64 + mt * 16 + g * 4 + r,
                           n0 + wn * 64 + nt * 16 + r16, N, blockIdx.z, ep);
}

// ---------------------------------------------------------------------------
// Split-K reduce: out[i] += p0[i]  (4096x1024 fp32, float4).
// ---------------------------------------------------------------------------
__global__ __launch_bounds__(256) void reduce_add(const float* __restrict__ p,
                                                  float* __restrict__ out) {
  const int i = blockIdx.x * 256 + threadIdx.x;
  float4 a = ((const float4*)p)[i];
  float4 b = ((float4*)out)[i];
  b.x += a.x; b.y += a.y; b.z += a.z; b.w += a.w;
  ((float4*)out)[i] = b;
}

// ---------------------------------------------------------------------------
// Flash attention (unchanged from R4): swapped-operand 32x32x16, frag-stream
// I/O, K dbuf, XCD-grouped blocks, in-register softmax, defer-max.
// ---------------------------------------------------------------------------
struct AttnState {
  f32x16 o0, o1;
  float m, lsum;
};

DEV void load_k(const unsigned short* kbase, int s, bf16x8 k0[4], bf16x8 k1[4]) {
  const unsigned short* p = kbase + (size_t)(s >> 5) * 2048;
#pragma unroll
  for (int kk = 0; kk < 4; ++kk) {
    k0[kk] = *(const bf16x8*)(p + kk * 512);
    k1[kk] = *(const bf16x8*)(p + 2048 + kk * 512);
  }
}

DEV void attn_tile(const bf16x8 k0[4], const bf16x8 k1[4],
                   const bf16x8 v0[4], const bf16x8 v1[4],
                   const bf16x8 qf[4], AttnState& st) {
  const f32x16 z16 = {0.f};
  f32x16 pA = z16, pB = z16;
  __builtin_amdgcn_s_setprio(1);
#pragma unroll
  for (int kk = 0; kk < 4; ++kk) {
    pA = __builtin_amdgcn_mfma_f32_32x32x16_bf16(k0[kk], qf[kk], pA, 0, 0, 0);
    pB = __builtin_amdgcn_mfma_f32_32x32x16_bf16(k1[kk], qf[kk], pB, 0, 0, 0);
  }
  __builtin_amdgcn_s_setprio(0);
  float m0 = fmaxf(pA[0], pB[0]), m1 = fmaxf(pA[1], pB[1]);
  float m2 = fmaxf(pA[2], pB[2]), m3 = fmaxf(pA[3], pB[3]);
#pragma unroll
  for (int r = 4; r < 16; r += 4) {
    m0 = fmaxf(m0, fmaxf(pA[r + 0], pB[r + 0]));
    m1 = fmaxf(m1, fmaxf(pA[r + 1], pB[r + 1]));
    m2 = fmaxf(m2, fmaxf(pA[r + 2], pB[r + 2]));
    m3 = fmaxf(m3, fmaxf(pA[r + 3], pB[r + 3]));
  }
  float mx = fmaxf(fmaxf(m0, m1), fmaxf(m2, m3));
  mx = fmaxf(mx, __shfl_xor(mx, 32));
  if (__any(mx > st.m + 8.f)) {
    const float mnew = fmaxf(st.m, mx);
    const float corr = __expf(st.m - mnew);
#pragma unroll
    for (int r = 0; r < 16; ++r) { st.o0[r] *= corr; st.o1[r] *= corr; }
    st.lsum *= corr;
    st.m = mnew;
  }
  float ps = 0.f;
#pragma unroll
  for (int r = 0; r < 16; ++r) {
    pA[r] = __expf(pA[r] - st.m); ps += pA[r];
    pB[r] = __expf(pB[r] - st.m); ps += pB[r];
  }
  ps += __shfl_xor(ps, 32);
  st.lsum += ps;
  bf16x8 pw[4];
#pragma unroll
  for (int w = 0; w < 4; ++w) {
    unsigned int wd0, wd1, wd2, wd3;
    const int e0 = (w & 1) * 8;
    if (w < 2) {
      asm("v_cvt_pk_bf16_f32 %0, %1, %2" : "=v"(wd0) : "v"(pA[e0 + 0]), "v"(pA[e0 + 1]));
      asm("v_cvt_pk_bf16_f32 %0, %1, %2" : "=v"(wd1) : "v"(pA[e0 + 2]), "v"(pA[e0 + 3]));
      asm("v_cvt_pk_bf16_f32 %0, %1, %2" : "=v"(wd2) : "v"(pA[e0 + 4]), "v"(pA[e0 + 5]));
      asm("v_cvt_pk_bf16_f32 %0, %1, %2" : "=v"(wd3) : "v"(pA[e0 + 6]), "v"(pA[e0 + 7]));
    } else {
      asm("v_cvt_pk_bf16_f32 %0, %1, %2" : "=v"(wd0) : "v"(pB[e0 + 0]), "v"(pB[e0 + 1]));
      asm("v_cvt_pk_bf16_f32 %0, %1, %2" : "=v"(wd1) : "v"(pB[e0 + 2]), "v"(pB[e0 + 3]));
      asm("v_cvt_pk_bf16_f32 %0, %1, %2" : "=v"(wd2) : "v"(pB[e0 + 4]), "v"(pB[e0 + 5]));
      asm("v_cvt_pk_bf16_f32 %0, %1, %2" : "=v"(wd3) : "v"(pB[e0 + 6]), "v"(pB[e0 + 7]));
    }
    u32x4 wv = {wd0, wd1, wd2, wd3};
    pw[w] = __builtin_bit_cast(bf16x8, wv);
  }
  __builtin_amdgcn_s_setprio(1);
#pragma unroll
  for (int w = 0; w < 4; ++w) {
    st.o0 = __builtin_amdgcn_mfma_f32_32x32x16_bf16(v0[w], pw[w], st.o0, 0, 0, 0);
    st.o1 = __builtin_amdgcn_mfma_f32_32x32x16_bf16(v1[w], pw[w], st.o1, 0, 0, 0);
  }
  __builtin_amdgcn_s_setprio(0);
}

__global__ __launch_bounds__(256, 2) void attn_kernel(
    const unsigned short* __restrict__ Qc, const unsigned short* __restrict__ Kc,
    const unsigned short* __restrict__ Vt, unsigned short* __restrict__ Oc) {
  const int lane = threadIdx.x & 63, wave = threadIdx.x >> 6;
  const int hi = lane >> 5, l31 = lane & 31;
  const int i = blockIdx.x;
  const int k8 = i & 7, mq = i >> 3;
  const int grp = k8 + 8 * (mq >> 4);
  const int qb = mq & 15;
  const int b = grp >> 4, h = grp & 15;
  const int q0 = qb * 128 + wave * 32;

  const unsigned short* qbp = Qc + ((size_t)grp * 64 + (q0 >> 5)) * 2048 + lane * 8;
  const unsigned short* kbp = Kc + (size_t)grp * 64 * 2048 + lane * 8;
  const unsigned short* vbp = Vt + (size_t)grp * 32 * 4096 + lane * 8;

  bf16x8 qf[4];
#pragma unroll
  for (int kk = 0; kk < 4; ++kk) qf[kk] = *(const bf16x8*)(qbp + kk * 512);

  AttnState st;
#pragma unroll
  for (int r = 0; r < 16; ++r) { st.o0[r] = 0.f; st.o1[r] = 0.f; }
  st.m = -1e30f; st.lsum = 0.f;

  bf16x8 kA0[4], kA1[4], kB0[4], kB1[4];
  load_k(kbp, 0, kA0, kA1);

  for (int s0 = 0; s0 < SEQ; s0 += 128) {
    const unsigned short* vt0 = vbp + (size_t)(s0 >> 6) * 4096;
    bf16x8 v0[4], v1[4];
#pragma unroll
    for (int w = 0; w < 4; ++w) {
      v0[w] = *(const bf16x8*)(vt0 + w * 512);
      v1[w] = *(const bf16x8*)(vt0 + 2048 + w * 512);
    }
    load_k(kbp, s0 + 64, kB0, kB1);
    attn_tile(kA0, kA1, v0, v1, qf, st);
    const unsigned short* vt1 = vbp + (size_t)((s0 + 64) >> 6) * 4096;
#pragma unroll
    for (int w = 0; w < 4; ++w) {
      v0[w] = *(const bf16x8*)(vt1 + w * 512);
      v1[w] = *(const bf16x8*)(vt1 + 2048 + w * 512);
    }
    const int snext = (s0 + 128 < SEQ) ? (s0 + 128) : 0;
    load_k(kbp, snext, kA0, kA1);
    attn_tile(kB0, kB1, v0, v1, qf, st);
  }

  const float inv = 1.0f / st.lsum;
  const size_t rowbase = (size_t)b * SEQ;
  unsigned short* op = Oc + (rowbase + q0 + l31) * DM + h * DKH + hi * 4;
#pragma unroll
  for (int dblk = 0; dblk < 2; ++dblk)
#pragma unroll
    for (int g4 = 0; g4 < 4; ++g4) {
      u16x4 stv;
#pragma unroll
      for (int r = 0; r < 4; ++r) {
        const float v = (dblk ? st.o1[g4 * 4 + r] : st.o0[g4 * 4 + r]) * inv;
        stv[r] = f2bf(v);
      }
      *(u16x4*)(op + dblk * 32 + g4 * 8) = stv;
    }
}

// ---------------------------------------------------------------------------
extern "C" void kernel_launch(void* const* d_in, const int* in_sizes, int n_in,
                              void* d_out, int out_size, void* d_ws,
                              size_t ws_size, hipStream_t stream) {
  (void)in_sizes; (void)n_in; (void)out_size; (void)ws_size;
  const float* x   = (const float*)d_in[0];
  const float* Wq  = (const float*)d_in[1];
  const float* Wk  = (const float*)d_in[2];
  const float* Wv  = (const float*)d_in[3];
  const float* Wo  = (const float*)d_in[4];
  const float* W1  = (const float*)d_in[5];
  const float* b1  = (const float*)d_in[6];
  const float* W2  = (const float*)d_in[7];
  const float* b2  = (const float*)d_in[8];
  const float* g1  = (const float*)d_in[9];
  const float* be1 = (const float*)d_in[10];
  const float* g2  = (const float*)d_in[11];
  const float* be2 = (const float*)d_in[12];
  float* out = (float*)d_out;

  char* ws = (char*)d_ws;
  const size_t MB = 1024 * 1024;
  unsigned short* h_buf  = (unsigned short*)(ws + 0 * MB);
  unsigned short* wqkv_t = (unsigned short*)(ws + 8 * MB);
  unsigned short* wo_t   = (unsigned short*)(ws + 14 * MB);
  unsigned short* w1_t   = (unsigned short*)(ws + 16 * MB);
  unsigned short* w2_t   = (unsigned short*)(ws + 24 * MB);
  unsigned short* q_attn = (unsigned short*)(ws + 32 * MB);
  unsigned short* k_attn = (unsigned short*)(ws + 40 * MB);
  unsigned short* v_attn = (unsigned short*)(ws + 48 * MB);
  unsigned short* ffn1   = (unsigned short*)(ws + 32 * MB);  // overlaps q/k/v
  float*          p0     = (float*)(ws + 0 * MB);  // 16MB; overlaps h_buf/
                                                   // wqkv_t/wo_t (dead @FFN2)

  EpiArgs e0 = {}; e0.q = q_attn; e0.k = k_attn; e0.vt = v_attn;
  EpiArgs e1 = {}; e1.of32 = out; e1.resid = x;
  EpiArgs e2 = {}; e2.ob16 = ffn1; e2.bias = b1;
  EpiArgs e4 = {}; e4.of32 = out; e4.p0 = p0; e4.bias = b2;

  convert_weights<<<12288, 256, 0, stream>>>(Wq, Wk, Wv, Wo, W1, W2,
                                             wqkv_t, wo_t, w1_t, w2_t);
  ln_kernel<<<NTOK, 256, 0, stream>>>(x, g1, be1, h_buf);
  gemm_bt<0><<<dim3(3072 / 128, NTOK / 128), 256, 0, stream>>>(
      h_buf, wqkv_t, NTOK, 3072, DM, e0);
  attn_kernel<<<512, 256, 0, stream>>>(q_attn, k_attn, v_attn, h_buf);
  gemm_pipe<1><<<dim3(DM / 128, NTOK / 128, 1), 256, 0, stream>>>(
      h_buf, wo_t, DM, DM, DM, e1);
  ln_kernel<<<NTOK, 256, 0, stream>>>(out, g2, be2, h_buf);
  gemm_bt<2><<<dim3(DFF / 128, NTOK / 128), 256, 0, stream>>>(
      h_buf, w1_t, NTOK, DFF, DM, e2);
  gemm_pipe<4><<<dim3(DM / 128, NTOK / 128, 2), 256, 0, stream>>>(
      ffn1, w2_t, DM, DFF / 2, DFF, e4);
  reduce_add<<<4096, 256, 0, stream>>>(p0, out);
}

// Round 6
// 300.022 us; speedup vs baseline: 1.5104x; 1.0543x over previous
//
#include <hip/hip_runtime.h>
#include <stdint.h>

// ---------------------------------------------------------------------------
// TransformerBlock: pre-LN MHA + pre-LN FFN(GELU), bf16 MFMA internals.
// B=2 S=2048 D=1024 H=16 dk=64 Dff=4096.
// R6: ALL four GEMMs on the pipelined structure (BK=64, explicit LDS dbuf,
// prefetch-before-compute, chunk-XOR swizzle, setprio) -- R5 proved it ~2x
// the m97 single-buffer structure on FFN2.  GELU erf via A&S 7.1.26 poly
// (max err 1.5e-7, ~half the libm erff VALU cost).  Attention unchanged.
// Workspace layout (64 MB):
//   [ 0MB) h_buf [4096,1024]bf16 (h1/attn/h2)   } 0-16MB dead at FFN2 time ->
//   [ 8MB) wqkv_t[3072,1024]bf16                }   p0 fp32 partial (16MB)
//   [14MB) wo_t  [1024,1024]bf16                }
//   [16MB) w1_t  [4096,1024]bf16
//   [24MB) w2_t  [1024,4096]bf16
//   [32MB) q_attn frag-stream 8MB   } overlapped by ffn1 [4096,4096] bf16
//   [40MB) k_attn frag-stream 8MB   }
//   [48MB) v_attn frag-stream 8MB
// d_out doubles as x2 (attn residual) between the Wo GEMM and FFN2.
// ---------------------------------------------------------------------------

typedef __attribute__((ext_vector_type(8))) short bf16x8;
typedef __attribute__((ext_vector_type(4))) float f32x4;
typedef __attribute__((ext_vector_type(16))) float f32x16;
typedef __attribute__((ext_vector_type(4))) unsigned short u16x4;
typedef __attribute__((ext_vector_type(4))) unsigned int u32x4;

#define DEV __device__ __forceinline__

static constexpr int DM   = 1024;
static constexpr int DFF  = 4096;
static constexpr int NH   = 16;
static constexpr int DKH  = 64;
static constexpr int SEQ  = 2048;
static constexpr int NBAT = 2;
static constexpr int NTOK = NBAT * SEQ;  // 4096

DEV unsigned short f2bf(float f) {
  union { float f; unsigned int u; } v; v.f = f;
  unsigned int u = v.u;
  return (unsigned short)((u + 0x7fffu + ((u >> 16) & 1u)) >> 16);
}

DEV void gload_lds16(const unsigned short* g, unsigned short* l) {
  __builtin_amdgcn_global_load_lds(
      (const __attribute__((address_space(1))) unsigned int*)g,
      (__attribute__((address_space(3))) unsigned int*)l, 16, 0, 0);
}

// A&S 7.1.26 erf (|err| <= 1.5e-7), exact-GELU epilogue helper.
DEV float fast_gelu(float x) {
  const float z = fabsf(x) * 0.70710678118654752f;
  const float t = __builtin_amdgcn_rcpf(1.0f + 0.3275911f * z);
  float p = 1.061405429f;
  p = p * t - 1.453152027f;
  p = p * t + 1.421413741f;
  p = p * t - 0.284496736f;
  p = p * t + 0.254829592f;
  p = p * t;
  float erfv = 1.0f - p * __expf(-z * z);
  erfv = copysignf(erfv, x);
  return 0.5f * x * (1.0f + erfv);
}

// ---------------------------------------------------------------------------
// LayerNorm: x fp32 [rows,1024] -> bf16 out. One block (256 thr) per row.
// ---------------------------------------------------------------------------
__global__ __launch_bounds__(256) void ln_kernel(
    const float* __restrict__ x, const float* __restrict__ g,
    const float* __restrict__ be, unsigned short* __restrict__ out) {
  const int row = blockIdx.x;
  const int t = threadIdx.x;
  const int lane = t & 63, w = t >> 6;
  const float4* xr = (const float4*)(x + (size_t)row * DM);
  float4 v = xr[t];
  float s  = v.x + v.y + v.z + v.w;
  float s2 = v.x * v.x + v.y * v.y + v.z * v.z + v.w * v.w;
#pragma unroll
  for (int off = 32; off; off >>= 1) {
    s  += __shfl_down(s, off);
    s2 += __shfl_down(s2, off);
  }
  __shared__ float rs_[4], rq_[4];
  if (lane == 0) { rs_[w] = s; rq_[w] = s2; }
  __syncthreads();
  float fs = rs_[0] + rs_[1] + rs_[2] + rs_[3];
  float fq = rq_[0] + rq_[1] + rq_[2] + rq_[3];
  float mu = fs * (1.0f / DM);
  float var = fq * (1.0f / DM) - mu * mu;
  float rstd = rsqrtf(var + 1e-5f);
  float4 gv = ((const float4*)g)[t];
  float4 bv = ((const float4*)be)[t];
  u16x4 o;
  o[0] = f2bf((v.x - mu) * rstd * gv.x + bv.x);
  o[1] = f2bf((v.y - mu) * rstd * gv.y + bv.y);
  o[2] = f2bf((v.z - mu) * rstd * gv.z + bv.z);
  o[3] = f2bf((v.w - mu) * rstd * gv.w + bv.w);
  *(u16x4*)(out + (size_t)row * DM + t * 4) = o;
}

// ---------------------------------------------------------------------------
// Weight convert: fp32 -> bf16 B^T layouts, one flat grid-stride kernel.
// ---------------------------------------------------------------------------
__global__ __launch_bounds__(256) void convert_weights(
    const float* __restrict__ Wq, const float* __restrict__ Wk,
    const float* __restrict__ Wv, const float* __restrict__ Wo,
    const float* __restrict__ W1, const float* __restrict__ W2,
    unsigned short* __restrict__ wqkv_t, unsigned short* __restrict__ wo_t,
    unsigned short* __restrict__ w1_t, unsigned short* __restrict__ w2_t) {
  const int NQKV = 3 * DM * DM;
  const int NWO  = DM * DM;
  const int NW1  = DM * DFF;
  const int NW2  = DM * DFF;
  const int total = NQKV + NWO + NW1 + NW2;
  for (int idx = blockIdx.x * 256 + threadIdx.x; idx < total;
       idx += gridDim.x * 256) {
    if (idx < NQKV) {
      int n = idx >> 10, d = idx & 1023;
      int which = n >> 10, nn = n & 1023, h = nn >> 6, kk = nn & 63;
      const float* W = (which == 0) ? Wq : (which == 1) ? Wk : Wv;
      wqkv_t[idx] = f2bf(W[((h << 10) + d) * 64 + kk]);
    } else if (idx < NQKV + NWO) {
      int i = idx - NQKV;
      int n = i >> 10, d = i & 1023;
      wo_t[i] = f2bf(Wo[(d << 10) + n]);
    } else if (idx < NQKV + NWO + NW1) {
      int i = idx - NQKV - NWO;
      int n = i >> 10, d = i & 1023;           // n: 0..4095 (Dff)
      w1_t[i] = f2bf(W1[d * DFF + n]);
    } else {
      int i = idx - NQKV - NWO - NW1;
      int n = i >> 12, s = i & 4095;           // n: 0..1023, s: 0..4095
      w2_t[i] = f2bf(W2[s * DM + n]);
    }
  }
}

// ---------------------------------------------------------------------------
struct EpiArgs {
  unsigned short* q;     // EPI0 (frag-stream)
  unsigned short* k;     // EPI0 (frag-stream)
  unsigned short* vt;    // EPI0 (frag-stream, kv bit2<->3 folded)
  unsigned short* ob16;  // EPI2
  float* of32;           // EPI1 / EPI4(z=1)
  float* p0;             // EPI4(z=0) fp32 partial
  const float* bias;     // EPI2 / EPI4
  const float* resid;    // EPI1
};

template <int EPI>
DEV void epilogue_elem(float v, int row, int col, int N, int bz,
                       const EpiArgs& ep) {
  if constexpr (EPI == 0) {  // QKV -> fragment-stream scratch layouts
    const int bb = row >> 11, rr = row & 2047;
    if (col < 1024) {        // Q (pre-scaled by 1/sqrt(dk))
      const int hh = col >> 6, dk = col & 63;
      const int kk = dk >> 4, h8 = (dk >> 3) & 1, e = dk & 7;
      const int qblk = rr >> 5, l31 = rr & 31;
      ep.q[((size_t)(bb * NH + hh) * 64 + qblk) * 2048 + kk * 512 +
           (h8 * 32 + l31) * 8 + e] = f2bf(v * 0.125f);
    } else if (col < 2048) { // K
      const int c = col - 1024;
      const int hh = c >> 6, dk = c & 63;
      const int kk = dk >> 4, h8 = (dk >> 3) & 1, e = dk & 7;
      const int kvblk = rr >> 5, l31 = rr & 31;
      ep.k[((size_t)(bb * NH + hh) * 64 + kvblk) * 2048 + kk * 512 +
           (h8 * 32 + l31) * 8 + e] = f2bf(v);
    } else {                 // V (kv bit2<->3 swizzle folded in)
      const int c = col - 2048, hh = c >> 6, dd = c & 63;
      const int ssw = (rr & ~12) | ((rr & 4) << 1) | ((rr & 8) >> 1);
      const int t64 = ssw >> 6, w = (ssw >> 4) & 3;
      const int h8 = (ssw >> 3) & 1, e = ssw & 7;
      const int dblk = dd >> 5, l31 = dd & 31;
      ep.vt[(((size_t)(bb * NH + hh) * 32 + t64) * 8 + dblk * 4 + w) * 512 +
            (h8 * 32 + l31) * 8 + e] = f2bf(v);
    }
  } else if constexpr (EPI == 1) {  // + residual -> fp32 (x2 into d_out)
    const size_t idx = (size_t)row * N + col;
    ep.of32[idx] = v + ep.resid[idx];
  } else if constexpr (EPI == 2) {  // + bias, exact GELU (A&S poly) -> bf16
    ep.ob16[(size_t)row * N + col] = f2bf(fast_gelu(v + ep.bias[col]));
  } else {  // EPI 4: FFN2 split-K. z=0 -> fp32 partial; z=1 -> out += v+bias
    const size_t idx = (size_t)row * N + col;
    if (bz == 0) ep.p0[idx] = v;
    else ep.of32[idx] = ep.of32[idx] + v + ep.bias[col];
  }
}

// ---------------------------------------------------------------------------
// Pipelined GEMM (2-phase, BK=64, explicit LDS double buffer): prefetch tile
// t+1 BEFORE computing tile t so the __syncthreads vmcnt-drain is short.
// Kc = per-chunk K; ldk = row stride; blockIdx.z = K-chunk (split-K).
// Chunk swizzle (both-sides involution): pos p in row holds chunk p^(row&7).
// ---------------------------------------------------------------------------
template <int EPI>
__global__ __launch_bounds__(256) void gemm_pipe(
    const unsigned short* __restrict__ A, const unsigned short* __restrict__ Bt,
    int N, int Kc, int ldk, EpiArgs ep) {
  __shared__ __align__(16) unsigned short Als[2][128 * 64];
  __shared__ __align__(16) unsigned short Bls[2][128 * 64];
  const int t = threadIdx.x, lane = t & 63, wave = t >> 6;
  const int wm = wave >> 1, wn = wave & 1;
  const int g = lane >> 4, r16 = lane & 15;
  const int m0 = blockIdx.y * 128, n0 = blockIdx.x * 128;
  const int kbase = blockIdx.z * Kc;

  f32x4 acc[4][4];
  const f32x4 z4 = {0.f, 0.f, 0.f, 0.f};
#pragma unroll
  for (int i = 0; i < 4; ++i)
#pragma unroll
    for (int j = 0; j < 4; ++j) acc[i][j] = z4;

  auto stage = [&](int b, int k0) {
#pragma unroll
    for (int i = 0; i < 4; ++i) {
      const int cb = i * 256 + wave * 64;       // wave-uniform chunk base
      const int c = cb + lane;
      const int row = c >> 3;
      const int sc = ((c & 7) ^ (row & 7)) * 8; // src-chunk swizzle (8 chunks)
      gload_lds16(A + (size_t)(m0 + row) * ldk + kbase + k0 + sc, &Als[b][cb * 8]);
      gload_lds16(Bt + (size_t)(n0 + row) * ldk + kbase + k0 + sc, &Bls[b][cb * 8]);
    }
  };

  const int NT = Kc >> 6;
  stage(0, 0);
  __syncthreads();
  for (int kt = 0; kt < NT; ++kt) {
    const int cur = kt & 1;
    if (kt + 1 < NT) stage(cur ^ 1, (kt + 1) << 6);  // prefetch next tile
    const int sw = r16 & 7;
    bf16x8 af[2][4], bfr[2][4];
#pragma unroll
    for (int ks = 0; ks < 2; ++ks) {
#pragma unroll
      for (int mt = 0; mt < 4; ++mt)
        af[ks][mt] = *(const bf16x8*)&Als[cur][(wm * 64 + mt * 16 + r16) * 64 +
                                              (((ks << 2) | g) ^ sw) * 8];
#pragma unroll
      for (int nt = 0; nt < 4; ++nt)
        bfr[ks][nt] = *(const bf16x8*)&Bls[cur][(wn * 64 + nt * 16 + r16) * 64 +
                                               (((ks << 2) | g) ^ sw) * 8];
    }
    __builtin_amdgcn_s_setprio(1);
#pragma unroll
    for (int ks = 0; ks < 2; ++ks)
#pragma unroll
      for (int mt = 0; mt < 4; ++mt)
#pragma unroll
        for (int nt = 0; nt < 4; ++nt)
          acc[mt][nt] = __builtin_amdgcn_mfma_f32_16x16x32_bf16(
              af[ks][mt], bfr[ks][nt], acc[mt][nt], 0, 0, 0);
    __builtin_amdgcn_s_setprio(0);
    __syncthreads();  // drains prefetch vmcnt (already ~landed) + LDS reuse
  }
#pragma unroll
  for (int mt = 0; mt < 4; ++mt)
#pragma unroll
    for (int nt = 0; nt < 4; ++nt)
#pragma unroll
      for (int r = 0; r < 4; ++r)
        epilogue_elem<EPI>(acc[mt][nt][r], m0 + wm * 64 + mt * 16 + g * 4 + r,
                           n0 + wn * 64 + nt * 16 + r16, N, blockIdx.z, ep);
}

// ---------------------------------------------------------------------------
// Split-K reduce: out[i] += p0[i]  (4096x1024 fp32, float4).
// ---------------------------------------------------------------------------
__global__ __launch_bounds__(256) void reduce_add(const float* __restrict__ p,
                                                  float* __restrict__ out) {
  const int i = blockIdx.x * 256 + threadIdx.x;
  float4 a = ((const float4*)p)[i];
  float4 b = ((float4*)out)[i];
  b.x += a.x; b.y += a.y; b.z += a.z; b.w += a.w;
  ((float4*)out)[i] = b;
}

// ---------------------------------------------------------------------------
// Flash attention (unchanged from R4): swapped-operand 32x32x16, frag-stream
// I/O, K dbuf, XCD-grouped blocks, in-register softmax, defer-max.
// ---------------------------------------------------------------------------
struct AttnState {
  f32x16 o0, o1;
  float m, lsum;
};

DEV void load_k(const unsigned short* kbase, int s, bf16x8 k0[4], bf16x8 k1[4]) {
  const unsigned short* p = kbase + (size_t)(s >> 5) * 2048;
#pragma unroll
  for (int kk = 0; kk < 4; ++kk) {
    k0[kk] = *(const bf16x8*)(p + kk * 512);
    k1[kk] = *(const bf16x8*)(p + 2048 + kk * 512);
  }
}

DEV void attn_tile(const bf16x8 k0[4], const bf16x8 k1[4],
                   const bf16x8 v0[4], const bf16x8 v1[4],
                   const bf16x8 qf[4], AttnState& st) {
  const f32x16 z16 = {0.f};
  f32x16 pA = z16, pB = z16;
  __builtin_amdgcn_s_setprio(1);
#pragma unroll
  for (int kk = 0; kk < 4; ++kk) {
    pA = __builtin_amdgcn_mfma_f32_32x32x16_bf16(k0[kk], qf[kk], pA, 0, 0, 0);
    pB = __builtin_amdgcn_mfma_f32_32x32x16_bf16(k1[kk], qf[kk], pB, 0, 0, 0);
  }
  __builtin_amdgcn_s_setprio(0);
  float m0 = fmaxf(pA[0], pB[0]), m1 = fmaxf(pA[1], pB[1]);
  float m2 = fmaxf(pA[2], pB[2]), m3 = fmaxf(pA[3], pB[3]);
#pragma unroll
  for (int r = 4; r < 16; r += 4) {
    m0 = fmaxf(m0, fmaxf(pA[r + 0], pB[r + 0]));
    m1 = fmaxf(m1, fmaxf(pA[r + 1], pB[r + 1]));
    m2 = fmaxf(m2, fmaxf(pA[r + 2], pB[r + 2]));
    m3 = fmaxf(m3, fmaxf(pA[r + 3], pB[r + 3]));
  }
  float mx = fmaxf(fmaxf(m0, m1), fmaxf(m2, m3));
  mx = fmaxf(mx, __shfl_xor(mx, 32));
  if (__any(mx > st.m + 8.f)) {
    const float mnew = fmaxf(st.m, mx);
    const float corr = __expf(st.m - mnew);
#pragma unroll
    for (int r = 0; r < 16; ++r) { st.o0[r] *= corr; st.o1[r] *= corr; }
    st.lsum *= corr;
    st.m = mnew;
  }
  float ps = 0.f;
#pragma unroll
  for (int r = 0; r < 16; ++r) {
    pA[r] = __expf(pA[r] - st.m); ps += pA[r];
    pB[r] = __expf(pB[r] - st.m); ps += pB[r];
  }
  ps += __shfl_xor(ps, 32);
  st.lsum += ps;
  bf16x8 pw[4];
#pragma unroll
  for (int w = 0; w < 4; ++w) {
    unsigned int wd0, wd1, wd2, wd3;
    const int e0 = (w & 1) * 8;
    if (w < 2) {
      asm("v_cvt_pk_bf16_f32 %0, %1, %2" : "=v"(wd0) : "v"(pA[e0 + 0]), "v"(pA[e0 + 1]));
      asm("v_cvt_pk_bf16_f32 %0, %1, %2" : "=v"(wd1) : "v"(pA[e0 + 2]), "v"(pA[e0 + 3]));
      asm("v_cvt_pk_bf16_f32 %0, %1, %2" : "=v"(wd2) : "v"(pA[e0 + 4]), "v"(pA[e0 + 5]));
      asm("v_cvt_pk_bf16_f32 %0, %1, %2" : "=v"(wd3) : "v"(pA[e0 + 6]), "v"(pA[e0 + 7]));
    } else {
      asm("v_cvt_pk_bf16_f32 %0, %1, %2" : "=v"(wd0) : "v"(pB[e0 + 0]), "v"(pB[e0 + 1]));
      asm("v_cvt_pk_bf16_f32 %0, %1, %2" : "=v"(wd1) : "v"(pB[e0 + 2]), "v"(pB[e0 + 3]));
      asm("v_cvt_pk_bf16_f32 %0, %1, %2" : "=v"(wd2) : "v"(pB[e0 + 4]), "v"(pB[e0 + 5]));
      asm("v_cvt_pk_bf16_f32 %0, %1, %2" : "=v"(wd3) : "v"(pB[e0 + 6]), "v"(pB[e0 + 7]));
    }
    u32x4 wv = {wd0, wd1, wd2, wd3};
    pw[w] = __builtin_bit_cast(bf16x8, wv);
  }
  __builtin_amdgcn_s_setprio(1);
#pragma unroll
  for (int w = 0; w < 4; ++w) {
    st.o0 = __builtin_amdgcn_mfma_f32_32x32x16_bf16(v0[w], pw[w], st.o0, 0, 0, 0);
    st.o1 = __builtin_amdgcn_mfma_f32_32x32x16_bf16(v1[w], pw[w], st.o1, 0, 0, 0);
  }
  __builtin_amdgcn_s_setprio(0);
}

__global__ __launch_bounds__(256, 2) void attn_kernel(
    const unsigned short* __restrict__ Qc, const unsigned short* __restrict__ Kc,
    const unsigned short* __restrict__ Vt, unsigned short* __restrict__ Oc) {
  const int lane = threadIdx.x & 63, wave = threadIdx.x >> 6;
  const int hi = lane >> 5, l31 = lane & 31;
  const int i = blockIdx.x;
  const int k8 = i & 7, mq = i >> 3;
  const int grp = k8 + 8 * (mq >> 4);
  const int qb = mq & 15;
  const int b = grp >> 4, h = grp & 15;
  const int q0 = qb * 128 + wave * 32;

  const unsigned short* qbp = Qc + ((size_t)grp * 64 + (q0 >> 5)) * 2048 + lane * 8;
  const unsigned short* kbp = Kc + (size_t)grp * 64 * 2048 + lane * 8;
  const unsigned short* vbp = Vt + (size_t)grp * 32 * 4096 + lane * 8;

  bf16x8 qf[4];
#pragma unroll
  for (int kk = 0; kk < 4; ++kk) qf[kk] = *(const bf16x8*)(qbp + kk * 512);

  AttnState st;
#pragma unroll
  for (int r = 0; r < 16; ++r) { st.o0[r] = 0.f; st.o1[r] = 0.f; }
  st.m = -1e30f; st.lsum = 0.f;

  bf16x8 kA0[4], kA1[4], kB0[4], kB1[4];
  load_k(kbp, 0, kA0, kA1);

  for (int s0 = 0; s0 < SEQ; s0 += 128) {
    const unsigned short* vt0 = vbp + (size_t)(s0 >> 6) * 4096;
    bf16x8 v0[4], v1[4];
#pragma unroll
    for (int w = 0; w < 4; ++w) {
      v0[w] = *(const bf16x8*)(vt0 + w * 512);
      v1[w] = *(const bf16x8*)(vt0 + 2048 + w * 512);
    }
    load_k(kbp, s0 + 64, kB0, kB1);
    attn_tile(kA0, kA1, v0, v1, qf, st);
    const unsigned short* vt1 = vbp + (size_t)((s0 + 64) >> 6) * 4096;
#pragma unroll
    for (int w = 0; w < 4; ++w) {
      v0[w] = *(const bf16x8*)(vt1 + w * 512);
      v1[w] = *(const bf16x8*)(vt1 + 2048 + w * 512);
    }
    const int snext = (s0 + 128 < SEQ) ? (s0 + 128) : 0;
    load_k(kbp, snext, kA0, kA1);
    attn_tile(kB0, kB1, v0, v1, qf, st);
  }

  const float inv = 1.0f / st.lsum;
  const size_t rowbase = (size_t)b * SEQ;
  unsigned short* op = Oc + (rowbase + q0 + l31) * DM + h * DKH + hi * 4;
#pragma unroll
  for (int dblk = 0; dblk < 2; ++dblk)
#pragma unroll
    for (int g4 = 0; g4 < 4; ++g4) {
      u16x4 stv;
#pragma unroll
      for (int r = 0; r < 4; ++r) {
        const float v = (dblk ? st.o1[g4 * 4 + r] : st.o0[g4 * 4 + r]) * inv;
        stv[r] = f2bf(v);
      }
      *(u16x4*)(op + dblk * 32 + g4 * 8) = stv;
    }
}

// ---------------------------------------------------------------------------
extern "C" void kernel_launch(void* const* d_in, const int* in_sizes, int n_in,
                              void* d_out, int out_size, void* d_ws,
                              size_t ws_size, hipStream_t stream) {
  (void)in_sizes; (void)n_in; (void)out_size; (void)ws_size;
  const float* x   = (const float*)d_in[0];
  const float* Wq  = (const float*)d_in[1];
  const float* Wk  = (const float*)d_in[2];
  const float* Wv  = (const float*)d_in[3];
  const float* Wo  = (const float*)d_in[4];
  const float* W1  = (const float*)d_in[5];
  const float* b1  = (const float*)d_in[6];
  const float* W2  = (const float*)d_in[7];
  const float* b2  = (const float*)d_in[8];
  const float* g1  = (const float*)d_in[9];
  const float* be1 = (const float*)d_in[10];
  const float* g2  = (const float*)d_in[11];
  const float* be2 = (const float*)d_in[12];
  float* out = (float*)d_out;

  char* ws = (char*)d_ws;
  const size_t MB = 1024 * 1024;
  unsigned short* h_buf  = (unsigned short*)(ws + 0 * MB);
  unsigned short* wqkv_t = (unsigned short*)(ws + 8 * MB);
  unsigned short* wo_t   = (unsigned short*)(ws + 14 * MB);
  unsigned short* w1_t   = (unsigned short*)(ws + 16 * MB);
  unsigned short* w2_t   = (unsigned short*)(ws + 24 * MB);
  unsigned short* q_attn = (unsigned short*)(ws + 32 * MB);
  unsigned short* k_attn = (unsigned short*)(ws + 40 * MB);
  unsigned short* v_attn = (unsigned short*)(ws + 48 * MB);
  unsigned short* ffn1   = (unsigned short*)(ws + 32 * MB);  // overlaps q/k/v
  float*          p0     = (float*)(ws + 0 * MB);  // 16MB; overlaps h_buf/
                                                   // wqkv_t/wo_t (dead @FFN2)

  EpiArgs e0 = {}; e0.q = q_attn; e0.k = k_attn; e0.vt = v_attn;
  EpiArgs e1 = {}; e1.of32 = out; e1.resid = x;
  EpiArgs e2 = {}; e2.ob16 = ffn1; e2.bias = b1;
  EpiArgs e4 = {}; e4.of32 = out; e4.p0 = p0; e4.bias = b2;

  convert_weights<<<12288, 256, 0, stream>>>(Wq, Wk, Wv, Wo, W1, W2,
                                             wqkv_t, wo_t, w1_t, w2_t);
  ln_kernel<<<NTOK, 256, 0, stream>>>(x, g1, be1, h_buf);
  gemm_pipe<0><<<dim3(3072 / 128, NTOK / 128, 1), 256, 0, stream>>>(
      h_buf, wqkv_t, 3072, DM, DM, e0);
  attn_kernel<<<512, 256, 0, stream>>>(q_attn, k_attn, v_attn, h_buf);
  gemm_pipe<1><<<dim3(DM / 128, NTOK / 128, 1), 256, 0, stream>>>(
      h_buf, wo_t, DM, DM, DM, e1);
  ln_kernel<<<NTOK, 256, 0, stream>>>(out, g2, be2, h_buf);
  gemm_pipe<2><<<dim3(DFF / 128, NTOK / 128, 1), 256, 0, stream>>>(
      h_buf, w1_t, DFF, DM, DM, e2);
  gemm_pipe<4><<<dim3(DM / 128, NTOK / 128, 2), 256, 0, stream>>>(
      ffn1, w2_t, DM, DFF / 2, DFF, e4);
  reduce_add<<<4096, 256, 0, stream>>>(p0, out);
}

// Round 7
// 259.171 us; speedup vs baseline: 1.7484x; 1.1576x over previous
//
#include <hip/hip_runtime.h>
#include <stdint.h>

// ---------------------------------------------------------------------------
// TransformerBlock: pre-LN MHA + pre-LN FFN(GELU), bf16 MFMA internals.
// B=2 S=2048 D=1024 H=16 dk=64 Dff=4096.
// R7: (a) weight convert rewritten as LDS-tiled 64x64 transpose (coalesced
// reads AND writes; was a 4-16KB-stride gather at 1 TB/s, 63us for 75MB);
// (b) bijective XCD-chunked block swizzle in gemm_pipe (T1) so each XCD's
// L2 sees a contiguous tile chunk (FFN1 FETCH 143MB -> ~75MB expected).
// GEMMs: pipelined BK=64 LDS-dbuf structure (R5/R6).  Attention: R4
// frag-stream swapped-operand kernel (unchanged).
// Workspace layout (64 MB):
//   [ 0MB) h_buf [4096,1024]bf16 (h1/attn/h2)   } 0-16MB dead at FFN2 time ->
//   [ 8MB) wqkv_t[3072,1024]bf16                }   p0 fp32 partial (16MB)
//   [14MB) wo_t  [1024,1024]bf16                }
//   [16MB) w1_t  [4096,1024]bf16
//   [24MB) w2_t  [1024,4096]bf16
//   [32MB) q_attn frag-stream 8MB   } overlapped by ffn1 [4096,4096] bf16
//   [40MB) k_attn frag-stream 8MB   }
//   [48MB) v_attn frag-stream 8MB
// d_out doubles as x2 (attn residual) between the Wo GEMM and FFN2.
// ---------------------------------------------------------------------------

typedef __attribute__((ext_vector_type(8))) short bf16x8;
typedef __attribute__((ext_vector_type(4))) float f32x4;
typedef __attribute__((ext_vector_type(16))) float f32x16;
typedef __attribute__((ext_vector_type(4))) unsigned short u16x4;
typedef __attribute__((ext_vector_type(4))) unsigned int u32x4;

#define DEV __device__ __forceinline__

static constexpr int DM   = 1024;
static constexpr int DFF  = 4096;
static constexpr int NH   = 16;
static constexpr int DKH  = 64;
static constexpr int SEQ  = 2048;
static constexpr int NBAT = 2;
static constexpr int NTOK = NBAT * SEQ;  // 4096

DEV unsigned short f2bf(float f) {
  union { float f; unsigned int u; } v; v.f = f;
  unsigned int u = v.u;
  return (unsigned short)((u + 0x7fffu + ((u >> 16) & 1u)) >> 16);
}

DEV void gload_lds16(const unsigned short* g, unsigned short* l) {
  __builtin_amdgcn_global_load_lds(
      (const __attribute__((address_space(1))) unsigned int*)g,
      (__attribute__((address_space(3))) unsigned int*)l, 16, 0, 0);
}

// A&S 7.1.26 erf (|err| <= 1.5e-7), exact-GELU epilogue helper.
DEV float fast_gelu(float x) {
  const float z = fabsf(x) * 0.70710678118654752f;
  const float t = __builtin_amdgcn_rcpf(1.0f + 0.3275911f * z);
  float p = 1.061405429f;
  p = p * t - 1.453152027f;
  p = p * t + 1.421413741f;
  p = p * t - 0.284496736f;
  p = p * t + 0.254829592f;
  p = p * t;
  float erfv = 1.0f - p * __expf(-z * z);
  erfv = copysignf(erfv, x);
  return 0.5f * x * (1.0f + erfv);
}

// ---------------------------------------------------------------------------
// LayerNorm: x fp32 [rows,1024] -> bf16 out. One block (256 thr) per row.
// ---------------------------------------------------------------------------
__global__ __launch_bounds__(256) void ln_kernel(
    const float* __restrict__ x, const float* __restrict__ g,
    const float* __restrict__ be, unsigned short* __restrict__ out) {
  const int row = blockIdx.x;
  const int t = threadIdx.x;
  const int lane = t & 63, w = t >> 6;
  const float4* xr = (const float4*)(x + (size_t)row * DM);
  float4 v = xr[t];
  float s  = v.x + v.y + v.z + v.w;
  float s2 = v.x * v.x + v.y * v.y + v.z * v.z + v.w * v.w;
#pragma unroll
  for (int off = 32; off; off >>= 1) {
    s  += __shfl_down(s, off);
    s2 += __shfl_down(s2, off);
  }
  __shared__ float rs_[4], rq_[4];
  if (lane == 0) { rs_[w] = s; rq_[w] = s2; }
  __syncthreads();
  float fs = rs_[0] + rs_[1] + rs_[2] + rs_[3];
  float fq = rq_[0] + rq_[1] + rq_[2] + rq_[3];
  float mu = fs * (1.0f / DM);
  float var = fq * (1.0f / DM) - mu * mu;
  float rstd = rsqrtf(var + 1e-5f);
  float4 gv = ((const float4*)g)[t];
  float4 bv = ((const float4*)be)[t];
  u16x4 o;
  o[0] = f2bf((v.x - mu) * rstd * gv.x + bv.x);
  o[1] = f2bf((v.y - mu) * rstd * gv.y + bv.y);
  o[2] = f2bf((v.z - mu) * rstd * gv.z + bv.z);
  o[3] = f2bf((v.w - mu) * rstd * gv.w + bv.w);
  *(u16x4*)(out + (size_t)row * DM + t * 4) = o;
}

// ---------------------------------------------------------------------------
// Weight convert: fp32 -> bf16 B^T via LDS-tiled 64x64 transpose.
// 3072 tiles: [0,768) QKV per-head [d][kk]->[kk][d]; [768,1024) Wo;
// [1024,2048) W1; [2048,3072) W2.  Coalesced reads (256B/wave) and writes
// (128B/wave); LDS [64][65] padding keeps both phases <=2-way (free).
// ---------------------------------------------------------------------------
__global__ __launch_bounds__(256) void transpose_weights(
    const float* __restrict__ Wq, const float* __restrict__ Wk,
    const float* __restrict__ Wv, const float* __restrict__ Wo,
    const float* __restrict__ W1, const float* __restrict__ W2,
    unsigned short* __restrict__ wqkv_t, unsigned short* __restrict__ wo_t,
    unsigned short* __restrict__ w1_t, unsigned short* __restrict__ w2_t) {
  __shared__ float lds[64][65];
  const int t = blockIdx.x;
  const float* inb; unsigned short* outb; int in_ld, out_ld;
  if (t < 768) {            // wqkv_t[n=which*1024+h*64+kk][d] = W[h][d][kk]
    const int slice = t >> 4, tin = t & 15;
    const int which = slice >> 4, h = slice & 15;
    const float* W = (which == 0) ? Wq : (which == 1) ? Wk : Wv;
    inb = W + (size_t)((h << 10) + (tin << 6)) * 64;
    in_ld = 64;
    outb = wqkv_t + ((size_t)((which << 10) + (h << 6)) << 10) + (tin << 6);
    out_ld = 1024;
  } else if (t < 1024) {    // wo_t[n][d] = Wo[d][n]
    const int tt = t - 768, tr = tt >> 4, tc = tt & 15;
    inb = Wo + (size_t)(tc << 6) * 1024 + (tr << 6); in_ld = 1024;
    outb = wo_t + (size_t)(tr << 6) * 1024 + (tc << 6); out_ld = 1024;
  } else if (t < 2048) {    // w1_t[n(4096)][d] = W1[d][n]
    const int tt = t - 1024, tr = tt >> 4, tc = tt & 15;
    inb = W1 + (size_t)(tc << 6) * 4096 + (tr << 6); in_ld = 4096;
    outb = w1_t + (size_t)(tr << 6) * 1024 + (tc << 6); out_ld = 1024;
  } else {                  // w2_t[n(1024)][s(4096)] = W2[s][n]
    const int tt = t - 2048, tr = tt >> 6, tc = tt & 63;
    inb = W2 + (size_t)(tc << 6) * 1024 + (tr << 6); in_ld = 1024;
    outb = w2_t + (size_t)(tr << 6) * 4096 + (tc << 6); out_ld = 4096;
  }
  const int j = threadIdx.x & 63, i0 = threadIdx.x >> 6;
#pragma unroll
  for (int p = 0; p < 16; ++p) {
    const int i = i0 + p * 4;
    lds[j][i] = inb[(size_t)i * in_ld + j];   // read row i coalesced
  }
  __syncthreads();
#pragma unroll
  for (int p = 0; p < 16; ++p) {
    const int r = i0 + p * 4;
    outb[(size_t)r * out_ld + j] = f2bf(lds[r][j]);  // write row r coalesced
  }
}

// ---------------------------------------------------------------------------
struct EpiArgs {
  unsigned short* q;     // EPI0 (frag-stream)
  unsigned short* k;     // EPI0 (frag-stream)
  unsigned short* vt;    // EPI0 (frag-stream, kv bit2<->3 folded)
  unsigned short* ob16;  // EPI2
  float* of32;           // EPI1 / EPI4(z=1)
  float* p0;             // EPI4(z=0) fp32 partial
  const float* bias;     // EPI2 / EPI4
  const float* resid;    // EPI1
};

template <int EPI>
DEV void epilogue_elem(float v, int row, int col, int N, int bz,
                       const EpiArgs& ep) {
  if constexpr (EPI == 0) {  // QKV -> fragment-stream scratch layouts
    const int bb = row >> 11, rr = row & 2047;
    if (col < 1024) {        // Q (pre-scaled by 1/sqrt(dk))
      const int hh = col >> 6, dk = col & 63;
      const int kk = dk >> 4, h8 = (dk >> 3) & 1, e = dk & 7;
      const int qblk = rr >> 5, l31 = rr & 31;
      ep.q[((size_t)(bb * NH + hh) * 64 + qblk) * 2048 + kk * 512 +
           (h8 * 32 + l31) * 8 + e] = f2bf(v * 0.125f);
    } else if (col < 2048) { // K
      const int c = col - 1024;
      const int hh = c >> 6, dk = c & 63;
      const int kk = dk >> 4, h8 = (dk >> 3) & 1, e = dk & 7;
      const int kvblk = rr >> 5, l31 = rr & 31;
      ep.k[((size_t)(bb * NH + hh) * 64 + kvblk) * 2048 + kk * 512 +
           (h8 * 32 + l31) * 8 + e] = f2bf(v);
    } else {                 // V (kv bit2<->3 swizzle folded in)
      const int c = col - 2048, hh = c >> 6, dd = c & 63;
      const int ssw = (rr & ~12) | ((rr & 4) << 1) | ((rr & 8) >> 1);
      const int t64 = ssw >> 6, w = (ssw >> 4) & 3;
      const int h8 = (ssw >> 3) & 1, e = ssw & 7;
      const int dblk = dd >> 5, l31 = dd & 31;
      ep.vt[(((size_t)(bb * NH + hh) * 32 + t64) * 8 + dblk * 4 + w) * 512 +
            (h8 * 32 + l31) * 8 + e] = f2bf(v);
    }
  } else if constexpr (EPI == 1) {  // + residual -> fp32 (x2 into d_out)
    const size_t idx = (size_t)row * N + col;
    ep.of32[idx] = v + ep.resid[idx];
  } else if constexpr (EPI == 2) {  // + bias, exact GELU (A&S poly) -> bf16
    ep.ob16[(size_t)row * N + col] = f2bf(fast_gelu(v + ep.bias[col]));
  } else {  // EPI 4: FFN2 split-K. z=0 -> fp32 partial; z=1 -> out += v+bias
    const size_t idx = (size_t)row * N + col;
    if (bz == 0) ep.p0[idx] = v;
    else ep.of32[idx] = ep.of32[idx] + v + ep.bias[col];
  }
}

// ---------------------------------------------------------------------------
// Pipelined GEMM (2-phase, BK=64, explicit LDS double buffer): prefetch tile
// t+1 BEFORE computing tile t so the __syncthreads vmcnt-drain is short.
// Kc = per-chunk K; ldk = row stride; blockIdx.z = K-chunk (split-K).
// Chunk swizzle (both-sides involution): pos p in row holds chunk p^(row&7).
// XCD-chunked block swizzle (T1): nwg%8==0 for all grids used here.
// ---------------------------------------------------------------------------
template <int EPI>
__global__ __launch_bounds__(256) void gemm_pipe(
    const unsigned short* __restrict__ A, const unsigned short* __restrict__ Bt,
    int N, int Kc, int ldk, EpiArgs ep) {
  __shared__ __align__(16) unsigned short Als[2][128 * 64];
  __shared__ __align__(16) unsigned short Bls[2][128 * 64];
  const int t = threadIdx.x, lane = t & 63, wave = t >> 6;
  const int wm = wave >> 1, wn = wave & 1;
  const int g = lane >> 4, r16 = lane & 15;
  // XCD-chunked swizzle: XCD k owns a contiguous chunk of block space.
  const int nx = gridDim.x;
  const int nwg = nx * gridDim.y;
  int wgid = blockIdx.y * nx + blockIdx.x;
  wgid = (wgid & 7) * (nwg >> 3) + (wgid >> 3);
  const int m0 = (wgid / nx) * 128, n0 = (wgid % nx) * 128;
  const int kbase = blockIdx.z * Kc;

  f32x4 acc[4][4];
  const f32x4 z4 = {0.f, 0.f, 0.f, 0.f};
#pragma unroll
  for (int i = 0; i < 4; ++i)
#pragma unroll
    for (int j = 0; j < 4; ++j) acc[i][j] = z4;

  auto stage = [&](int b, int k0) {
#pragma unroll
    for (int i = 0; i < 4; ++i) {
      const int cb = i * 256 + wave * 64;       // wave-uniform chunk base
      const int c = cb + lane;
      const int row = c >> 3;
      const int sc = ((c & 7) ^ (row & 7)) * 8; // src-chunk swizzle (8 chunks)
      gload_lds16(A + (size_t)(m0 + row) * ldk + kbase + k0 + sc, &Als[b][cb * 8]);
      gload_lds16(Bt + (size_t)(n0 + row) * ldk + kbase + k0 + sc, &Bls[b][cb * 8]);
    }
  };

  const int NT = Kc >> 6;
  stage(0, 0);
  __syncthreads();
  for (int kt = 0; kt < NT; ++kt) {
    const int cur = kt & 1;
    if (kt + 1 < NT) stage(cur ^ 1, (kt + 1) << 6);  // prefetch next tile
    const int sw = r16 & 7;
    bf16x8 af[2][4], bfr[2][4];
#pragma unroll
    for (int ks = 0; ks < 2; ++ks) {
#pragma unroll
      for (int mt = 0; mt < 4; ++mt)
        af[ks][mt] = *(const bf16x8*)&Als[cur][(wm * 64 + mt * 16 + r16) * 64 +
                                              (((ks << 2) | g) ^ sw) * 8];
#pragma unroll
      for (int nt = 0; nt < 4; ++nt)
        bfr[ks][nt] = *(const bf16x8*)&Bls[cur][(wn * 64 + nt * 16 + r16) * 64 +
                                               (((ks << 2) | g) ^ sw) * 8];
    }
    __builtin_amdgcn_s_setprio(1);
#pragma unroll
    for (int ks = 0; ks < 2; ++ks)
#pragma unroll
      for (int mt = 0; mt < 4; ++mt)
#pragma unroll
        for (int nt = 0; nt < 4; ++nt)
          acc[mt][nt] = __builtin_amdgcn_mfma_f32_16x16x32_bf16(
              af[ks][mt], bfr[ks][nt], acc[mt][nt], 0, 0, 0);
    __builtin_amdgcn_s_setprio(0);
    __syncthreads();  // drains prefetch vmcnt (already ~landed) + LDS reuse
  }
#pragma unroll
  for (int mt = 0; mt < 4; ++mt)
#pragma unroll
    for (int nt = 0; nt < 4; ++nt)
#pragma unroll
      for (int r = 0; r < 4; ++r)
        epilogue_elem<EPI>(acc[mt][nt][r], m0 + wm * 64 + mt * 16 + g * 4 + r,
                           n0 + wn * 64 + nt * 16 + r16, N, blockIdx.z, ep);
}

// ---------------------------------------------------------------------------
// Split-K reduce: out[i] += p0[i]  (4096x1024 fp32, float4).
// ---------------------------------------------------------------------------
__global__ __launch_bounds__(256) void reduce_add(const float* __restrict__ p,
                                                  float* __restrict__ out) {
  const int i = blockIdx.x * 256 + threadIdx.x;
  float4 a = ((const float4*)p)[i];
  float4 b = ((float4*)out)[i];
  b.x += a.x; b.y += a.y; b.z += a.z; b.w += a.w;
  ((float4*)out)[i] = b;
}

// ---------------------------------------------------------------------------
// Flash attention (unchanged from R4): swapped-operand 32x32x16, frag-stream
// I/O, K dbuf, XCD-grouped blocks, in-register softmax, defer-max.
// ---------------------------------------------------------------------------
struct AttnState {
  f32x16 o0, o1;
  float m, lsum;
};

DEV void load_k(const unsigned short* kbase, int s, bf16x8 k0[4], bf16x8 k1[4]) {
  const unsigned short* p = kbase + (size_t)(s >> 5) * 2048;
#pragma unroll
  for (int kk = 0; kk < 4; ++kk) {
    k0[kk] = *(const bf16x8*)(p + kk * 512);
    k1[kk] = *(const bf16x8*)(p + 2048 + kk * 512);
  }
}

DEV void attn_tile(const bf16x8 k0[4], const bf16x8 k1[4],
                   const bf16x8 v0[4], const bf16x8 v1[4],
                   const bf16x8 qf[4], AttnState& st) {
  const f32x16 z16 = {0.f};
  f32x16 pA = z16, pB = z16;
  __builtin_amdgcn_s_setprio(1);
#pragma unroll
  for (int kk = 0; kk < 4; ++kk) {
    pA = __builtin_amdgcn_mfma_f32_32x32x16_bf16(k0[kk], qf[kk], pA, 0, 0, 0);
    pB = __builtin_amdgcn_mfma_f32_32x32x16_bf16(k1[kk], qf[kk], pB, 0, 0, 0);
  }
  __builtin_amdgcn_s_setprio(0);
  float m0 = fmaxf(pA[0], pB[0]), m1 = fmaxf(pA[1], pB[1]);
  float m2 = fmaxf(pA[2], pB[2]), m3 = fmaxf(pA[3], pB[3]);
#pragma unroll
  for (int r = 4; r < 16; r += 4) {
    m0 = fmaxf(m0, fmaxf(pA[r + 0], pB[r + 0]));
    m1 = fmaxf(m1, fmaxf(pA[r + 1], pB[r + 1]));
    m2 = fmaxf(m2, fmaxf(pA[r + 2], pB[r + 2]));
    m3 = fmaxf(m3, fmaxf(pA[r + 3], pB[r + 3]));
  }
  float mx = fmaxf(fmaxf(m0, m1), fmaxf(m2, m3));
  mx = fmaxf(mx, __shfl_xor(mx, 32));
  if (__any(mx > st.m + 8.f)) {
    const float mnew = fmaxf(st.m, mx);
    const float corr = __expf(st.m - mnew);
#pragma unroll
    for (int r = 0; r < 16; ++r) { st.o0[r] *= corr; st.o1[r] *= corr; }
    st.lsum *= corr;
    st.m = mnew;
  }
  float ps = 0.f;
#pragma unroll
  for (int r = 0; r < 16; ++r) {
    pA[r] = __expf(pA[r] - st.m); ps += pA[r];
    pB[r] = __expf(pB[r] - st.m); ps += pB[r];
  }
  ps += __shfl_xor(ps, 32);
  st.lsum += ps;
  bf16x8 pw[4];
#pragma unroll
  for (int w = 0; w < 4; ++w) {
    unsigned int wd0, wd1, wd2, wd3;
    const int e0 = (w & 1) * 8;
    if (w < 2) {
      asm("v_cvt_pk_bf16_f32 %0, %1, %2" : "=v"(wd0) : "v"(pA[e0 + 0]), "v"(pA[e0 + 1]));
      asm("v_cvt_pk_bf16_f32 %0, %1, %2" : "=v"(wd1) : "v"(pA[e0 + 2]), "v"(pA[e0 + 3]));
      asm("v_cvt_pk_bf16_f32 %0, %1, %2" : "=v"(wd2) : "v"(pA[e0 + 4]), "v"(pA[e0 + 5]));
      asm("v_cvt_pk_bf16_f32 %0, %1, %2" : "=v"(wd3) : "v"(pA[e0 + 6]), "v"(pA[e0 + 7]));
    } else {
      asm("v_cvt_pk_bf16_f32 %0, %1, %2" : "=v"(wd0) : "v"(pB[e0 + 0]), "v"(pB[e0 + 1]));
      asm("v_cvt_pk_bf16_f32 %0, %1, %2" : "=v"(wd1) : "v"(pB[e0 + 2]), "v"(pB[e0 + 3]));
      asm("v_cvt_pk_bf16_f32 %0, %1, %2" : "=v"(wd2) : "v"(pB[e0 + 4]), "v"(pB[e0 + 5]));
      asm("v_cvt_pk_bf16_f32 %0, %1, %2" : "=v"(wd3) : "v"(pB[e0 + 6]), "v"(pB[e0 + 7]));
    }
    u32x4 wv = {wd0, wd1, wd2, wd3};
    pw[w] = __builtin_bit_cast(bf16x8, wv);
  }
  __builtin_amdgcn_s_setprio(1);
#pragma unroll
  for (int w = 0; w < 4; ++w) {
    st.o0 = __builtin_amdgcn_mfma_f32_32x32x16_bf16(v0[w], pw[w], st.o0, 0, 0, 0);
    st.o1 = __builtin_amdgcn_mfma_f32_32x32x16_bf16(v1[w], pw[w], st.o1, 0, 0, 0);
  }
  __builtin_amdgcn_s_setprio(0);
}

__global__ __launch_bounds__(256, 2) void attn_kernel(
    const unsigned short* __restrict__ Qc, const unsigned short* __restrict__ Kc,
    const unsigned short* __restrict__ Vt, unsigned short* __restrict__ Oc) {
  const int lane = threadIdx.x & 63, wave = threadIdx.x >> 6;
  const int hi = lane >> 5, l31 = lane & 31;
  const int i = blockIdx.x;
  const int k8 = i & 7, mq = i >> 3;
  const int grp = k8 + 8 * (mq >> 4);
  const int qb = mq & 15;
  const int b = grp >> 4, h = grp & 15;
  const int q0 = qb * 128 + wave * 32;

  const unsigned short* qbp = Qc + ((size_t)grp * 64 + (q0 >> 5)) * 2048 + lane * 8;
  const unsigned short* kbp = Kc + (size_t)grp * 64 * 2048 + lane * 8;
  const unsigned short* vbp = Vt + (size_t)grp * 32 * 4096 + lane * 8;

  bf16x8 qf[4];
#pragma unroll
  for (int kk = 0; kk < 4; ++kk) qf[kk] = *(const bf16x8*)(qbp + kk * 512);

  AttnState st;
#pragma unroll
  for (int r = 0; r < 16; ++r) { st.o0[r] = 0.f; st.o1[r] = 0.f; }
  st.m = -1e30f; st.lsum = 0.f;

  bf16x8 kA0[4], kA1[4], kB0[4], kB1[4];
  load_k(kbp, 0, kA0, kA1);

  for (int s0 = 0; s0 < SEQ; s0 += 128) {
    const unsigned short* vt0 = vbp + (size_t)(s0 >> 6) * 4096;
    bf16x8 v0[4], v1[4];
#pragma unroll
    for (int w = 0; w < 4; ++w) {
      v0[w] = *(const bf16x8*)(vt0 + w * 512);
      v1[w] = *(const bf16x8*)(vt0 + 2048 + w * 512);
    }
    load_k(kbp, s0 + 64, kB0, kB1);
    attn_tile(kA0, kA1, v0, v1, qf, st);
    const unsigned short* vt1 = vbp + (size_t)((s0 + 64) >> 6) * 4096;
#pragma unroll
    for (int w = 0; w < 4; ++w) {
      v0[w] = *(const bf16x8*)(vt1 + w * 512);
      v1[w] = *(const bf16x8*)(vt1 + 2048 + w * 512);
    }
    const int snext = (s0 + 128 < SEQ) ? (s0 + 128) : 0;
    load_k(kbp, snext, kA0, kA1);
    attn_tile(kB0, kB1, v0, v1, qf, st);
  }

  const float inv = 1.0f / st.lsum;
  const size_t rowbase = (size_t)b * SEQ;
  unsigned short* op = Oc + (rowbase + q0 + l31) * DM + h * DKH + hi * 4;
#pragma unroll
  for (int dblk = 0; dblk < 2; ++dblk)
#pragma unroll
    for (int g4 = 0; g4 < 4; ++g4) {
      u16x4 stv;
#pragma unroll
      for (int r = 0; r < 4; ++r) {
        const float v = (dblk ? st.o1[g4 * 4 + r] : st.o0[g4 * 4 + r]) * inv;
        stv[r] = f2bf(v);
      }
      *(u16x4*)(op + dblk * 32 + g4 * 8) = stv;
    }
}

// ---------------------------------------------------------------------------
extern "C" void kernel_launch(void* const* d_in, const int* in_sizes, int n_in,
                              void* d_out, int out_size, void* d_ws,
                              size_t ws_size, hipStream_t stream) {
  (void)in_sizes; (void)n_in; (void)out_size; (void)ws_size;
  const float* x   = (const float*)d_in[0];
  const float* Wq  = (const float*)d_in[1];
  const float* Wk  = (const float*)d_in[2];
  const float* Wv  = (const float*)d_in[3];
  const float* Wo  = (const float*)d_in[4];
  const float* W1  = (const float*)d_in[5];
  const float* b1  = (const float*)d_in[6];
  const float* W2  = (const float*)d_in[7];
  const float* b2  = (const float*)d_in[8];
  const float* g1  = (const float*)d_in[9];
  const float* be1 = (const float*)d_in[10];
  const float* g2  = (const float*)d_in[11];
  const float* be2 = (const float*)d_in[12];
  float* out = (float*)d_out;

  char* ws = (char*)d_ws;
  const size_t MB = 1024 * 1024;
  unsigned short* h_buf  = (unsigned short*)(ws + 0 * MB);
  unsigned short* wqkv_t = (unsigned short*)(ws + 8 * MB);
  unsigned short* wo_t   = (unsigned short*)(ws + 14 * MB);
  unsigned short* w1_t   = (unsigned short*)(ws + 16 * MB);
  unsigned short* w2_t   = (unsigned short*)(ws + 24 * MB);
  unsigned short* q_attn = (unsigned short*)(ws + 32 * MB);
  unsigned short* k_attn = (unsigned short*)(ws + 40 * MB);
  unsigned short* v_attn = (unsigned short*)(ws + 48 * MB);
  unsigned short* ffn1   = (unsigned short*)(ws + 32 * MB);  // overlaps q/k/v
  float*          p0     = (float*)(ws + 0 * MB);  // 16MB; overlaps h_buf/
                                                   // wqkv_t/wo_t (dead @FFN2)

  EpiArgs e0 = {}; e0.q = q_attn; e0.k = k_attn; e0.vt = v_attn;
  EpiArgs e1 = {}; e1.of32 = out; e1.resid = x;
  EpiArgs e2 = {}; e2.ob16 = ffn1; e2.bias = b1;
  EpiArgs e4 = {}; e4.of32 = out; e4.p0 = p0; e4.bias = b2;

  transpose_weights<<<3072, 256, 0, stream>>>(Wq, Wk, Wv, Wo, W1, W2,
                                              wqkv_t, wo_t, w1_t, w2_t);
  ln_kernel<<<NTOK, 256, 0, stream>>>(x, g1, be1, h_buf);
  gemm_pipe<0><<<dim3(3072 / 128, NTOK / 128, 1), 256, 0, stream>>>(
      h_buf, wqkv_t, 3072, DM, DM, e0);
  attn_kernel<<<512, 256, 0, stream>>>(q_attn, k_attn, v_attn, h_buf);
  gemm_pipe<1><<<dim3(DM / 128, NTOK / 128, 1), 256, 0, stream>>>(
      h_buf, wo_t, DM, DM, DM, e1);
  ln_kernel<<<NTOK, 256, 0, stream>>>(out, g2, be2, h_buf);
  gemm_pipe<2><<<dim3(DFF / 128, NTOK / 128, 1), 256, 0, stream>>>(
      h_buf, w1_t, DFF, DM, DM, e2);
  gemm_pipe<4><<<dim3(DM / 128, NTOK / 128, 2), 256, 0, stream>>>(
      ffn1, w2_t, DM, DFF / 2, DFF, e4);
  reduce_add<<<4096, 256, 0, stream>>>(p0, out);
}